// Round 15
// baseline (1521.484 us; speedup 1.0000x reference)
//
#include <hip/hip_runtime.h>
#include <stdint.h>

typedef unsigned short u16;
typedef __attribute__((ext_vector_type(8))) short bf16x8_t;
typedef __attribute__((ext_vector_type(4))) float f32x4_t;

__device__ __forceinline__ float bl(u16 x) {
  union { unsigned u; float f; } c; c.u = ((unsigned)x) << 16; return c.f;
}
__device__ __forceinline__ u16 fb(float x) {
  union { float f; unsigned u; } c; c.f = x;
  unsigned r = c.u + 0x7fffu + ((c.u >> 16) & 1u);
  return (u16)(r >> 16);
}

__global__ void sentinel_kernel(float* out, int n) {
  int i = blockIdx.x * 256 + threadIdx.x;
  if (i < n) out[i] = 12345.f;
}

// ---------------- weight transpose: wT[n][k] = fb(W[k][n]) ----------------
struct TSeg { const float* src; u16* dst; };
struct TArgs { TSeg s[23]; };
__global__ void transpose_w(TArgs a) {
  const float* src = a.s[blockIdx.x].src;
  u16* dst = a.s[blockIdx.x].dst;
  for (int e = threadIdx.x; e < 16384; e += 256) {
    int n = e >> 7, k = e & 127;
    dst[e] = fb(src[k * 128 + n]);
  }
}

// ---------------- CSR build + receiver-sort ----------------
__global__ void zero_i32(int* p, int n) {
  int i = blockIdx.x * 256 + threadIdx.x;
  if (i < n) p[i] = 0;
}
__global__ void deg_count(const int* __restrict__ ei, int* __restrict__ cnt, int E) {
  int e = blockIdx.x * 256 + threadIdx.x;
  if (e < E) atomicAdd(&cnt[ei[E + e]], 1);
}
__global__ void scan1(const int* __restrict__ cnt, int* __restrict__ part,
                      int* __restrict__ bsum, int N) {
  __shared__ int s[256];
  int i = blockIdx.x * 256 + threadIdx.x;
  s[threadIdx.x] = (i < N) ? cnt[i] : 0;
  __syncthreads();
#pragma unroll
  for (int o = 1; o < 256; o <<= 1) {
    int t = (threadIdx.x >= o) ? s[threadIdx.x - o] : 0;
    __syncthreads();
    s[threadIdx.x] += t;
    __syncthreads();
  }
  if (i < N) part[i] = s[threadIdx.x];
  if (threadIdx.x == 255) bsum[blockIdx.x] = s[255];
}
__global__ void scan2(int* bsum, int nb) {
  if (threadIdx.x == 0 && blockIdx.x == 0) {
    int acc = 0;
    for (int i = 0; i < nb; ++i) { int t = bsum[i]; bsum[i] = acc; acc += t; }
  }
}
__global__ void scan3(const int* __restrict__ part, const int* __restrict__ bsum,
                      int* __restrict__ start, int N) {
  int i = blockIdx.x * 256 + threadIdx.x;
  if (i < N) start[i + 1] = part[i] + bsum[i >> 8];
  if (i == 0) start[0] = 0;
}
__global__ void fill_slot(const int* __restrict__ ei, int* __restrict__ cnt2,
                          const int* __restrict__ start, int* __restrict__ sortedS,
                          int* __restrict__ sortedR, int E) {
  int e = blockIdx.x * 256 + threadIdx.x;
  if (e >= E) return;
  int s = ei[e], r = ei[E + e];
  int p = atomicAdd(&cnt2[r], 1);
  int slot = start[r] + p;
  sortedS[slot] = s;
  sortedR[slot] = r;
}

// ---------------- feature kernels ----------------
__global__ void node_feat_kernel(const float* __restrict__ t, const float* __restrict__ tp,
                                 const float* __restrict__ q, const float* __restrict__ qp,
                                 const float* __restrict__ qn, const float* __restrict__ nm,
                                 const float* __restrict__ ns, float* __restrict__ nfeat,
                                 int n_nodes) {
  int n = blockIdx.x * 256 + threadIdx.x;
  if (n >= n_nodes) return;
  float u = t[n];
  float x[9];
  x[0] = u; x[1] = u - tp[n];
  float hq = q[n];
  x[2] = hq; x[3] = hq - qp[n];
#pragma unroll
  for (int j = 0; j < 5; ++j) x[4 + j] = qn[n * 5 + j];
#pragma unroll
  for (int k = 0; k < 9; ++k) nfeat[n * 9 + k] = (x[k] - nm[k]) / ns[k];
}

__global__ void edge_feat_kernel(const int* __restrict__ sArr, const int* __restrict__ rArr,
                                 const float* __restrict__ mp, const float* __restrict__ u,
                                 const float* __restrict__ em, const float* __restrict__ es,
                                 float* __restrict__ efeat, int n_edges) {
  int e = blockIdx.x * 256 + threadIdx.x;
  if (e >= n_edges) return;
  int s = sArr[e], r = rArr[e];
  float rx = mp[s * 2] - mp[r * 2];
  float ry = mp[s * 2 + 1] - mp[r * 2 + 1];
  float d = sqrtf(rx * rx + ry * ry);
  float rt = u[s] - u[r];
  float x[4] = {rx, ry, d, rt};
#pragma unroll
  for (int k = 0; k < 4; ++k) efeat[e * 4 + k] = (x[k] - em[k]) / es[k];
}

template <int K>
__global__ void enc1_kernel(const float* __restrict__ feat, const float* __restrict__ w1,
                            const float* __restrict__ b1, u16* __restrict__ out, int M) {
  int gid = blockIdx.x * 256 + threadIdx.x;
  int n = gid >> 7, h = gid & 127;
  if (n >= M) return;
  float acc = b1[h];
#pragma unroll
  for (int k = 0; k < K; ++k) acc += feat[n * K + k] * w1[k * 128 + h];
  out[n * 128 + h] = fb(acc > 0.f ? acc : 0.f);
}

// ---------------- LDS-free-GEMM + LDS-staged vector-store epilogue ----------------
#define GM_NONE 0
#define GM_RELU 1
#define GM_LN 2

template <int MODE, bool DUAL, bool A0F32>
__global__ __launch_bounds__(256, 2) void gemm64(
    const void* __restrict__ A0v, const u16* __restrict__ WT0, const u16* __restrict__ A1,
    const u16* __restrict__ WT1, const float* __restrict__ bias, const float* __restrict__ gg,
    const float* __restrict__ bb, const u16* __restrict__ resid, u16* __restrict__ out, int M) {
  __shared__ u16 sO[64][136];
  const int tid = threadIdx.x;
  const int wave = tid >> 6, lane = tid & 63;
  const int q = lane >> 4, l16 = lane & 15;
  const int m0 = blockIdx.x * 64;
  int arow = m0 + wave * 16 + l16;
  if (arow >= M) arow = M - 1;

  f32x4_t acc[8];
#pragma unroll
  for (int b = 0; b < 8; ++b) acc[b] = (f32x4_t){0.f, 0.f, 0.f, 0.f};

  const int NKT = DUAL ? 2 : 1;
#pragma unroll 1
  for (int kt = 0; kt < NKT; ++kt) {
    const u16* WT = kt ? WT1 : WT0;
#pragma unroll
    for (int kk = 0; kk < 4; ++kk) {
      bf16x8_t af;
      if (A0F32 && kt == 0) {
        const float* ap = (const float*)A0v + (size_t)arow * 128 + kk * 32 + q * 8;
        union { u16 u[8]; bf16x8_t v; } cv;
#pragma unroll
        for (int j = 0; j < 8; ++j) cv.u[j] = fb(ap[j]);
        af = cv.v;
      } else {
        const u16* ap = (kt ? A1 : (const u16*)A0v) + (size_t)arow * 128 + kk * 32 + q * 8;
        af = *(const bf16x8_t*)ap;
      }
      const u16* wp = WT + kk * 32 + q * 8;
#pragma unroll
      for (int nt = 0; nt < 8; ++nt) {
        bf16x8_t bfv = *(const bf16x8_t*)(wp + (size_t)(nt * 16 + l16) * 128);
        acc[nt] = __builtin_amdgcn_mfma_f32_16x16x32_bf16(af, bfv, acc[nt], 0, 0, 0);
      }
    }
  }

  const int rowb = wave * 16 + q * 4;
  if (MODE == GM_NONE) {
#pragma unroll
    for (int r = 0; r < 4; ++r)
#pragma unroll
      for (int nt = 0; nt < 8; ++nt) sO[rowb + r][nt * 16 + l16] = fb(acc[nt][r]);
  } else if (MODE == GM_RELU) {
    float bcol[8];
#pragma unroll
    for (int nt = 0; nt < 8; ++nt) bcol[nt] = bias[nt * 16 + l16];
#pragma unroll
    for (int r = 0; r < 4; ++r)
#pragma unroll
      for (int nt = 0; nt < 8; ++nt) {
        float v = acc[nt][r] + bcol[nt];
        sO[rowb + r][nt * 16 + l16] = fb(v > 0.f ? v : 0.f);
      }
  } else {
    float bcol[8], gcol[8], becol[8];
#pragma unroll
    for (int nt = 0; nt < 8; ++nt) {
      bcol[nt] = bias[nt * 16 + l16];
      gcol[nt] = gg[nt * 16 + l16];
      becol[nt] = bb[nt * 16 + l16];
    }
    float s[4] = {0, 0, 0, 0}, ss[4] = {0, 0, 0, 0};
#pragma unroll
    for (int r = 0; r < 4; ++r)
#pragma unroll
      for (int nt = 0; nt < 8; ++nt) {
        float v = acc[nt][r] + bcol[nt];
        s[r] += v;
        ss[r] += v * v;
      }
#pragma unroll
    for (int r = 0; r < 4; ++r) {
#pragma unroll
      for (int m = 1; m <= 8; m <<= 1) {
        s[r] += __shfl_xor(s[r], m, 64);
        ss[r] += __shfl_xor(ss[r], m, 64);
      }
    }
#pragma unroll
    for (int r = 0; r < 4; ++r) {
      float mean = s[r] * (1.f / 128.f);
      float var = fmaxf(ss[r] * (1.f / 128.f) - mean * mean, 0.f);
      float rstd = rsqrtf(var + 1e-5f);
#pragma unroll
      for (int nt = 0; nt < 8; ++nt) {
        float v = (acc[nt][r] + bcol[nt] - mean) * rstd * gcol[nt] + becol[nt];
        sO[rowb + r][nt * 16 + l16] = fb(v);
      }
    }
  }
  __syncthreads();
#pragma unroll
  for (int it = 0; it < 4; ++it) {
    int lin = it * 256 + tid;
    int row = lin >> 4, ch = (lin & 15) * 8;
    int grow = m0 + row;
    if (grow >= M) continue;
    u16 o8[8];
    *(uint4*)o8 = *(uint4*)(&sO[row][ch]);
    if (MODE == GM_LN && resid) {
      u16 r8[8];
      *(uint4*)r8 = *(const uint4*)(resid + (size_t)grow * 128 + ch);
#pragma unroll
      for (int j = 0; j < 8; ++j) o8[j] = fb(bl(o8[j]) + bl(r8[j]));
    }
    *(uint4*)(out + (size_t)grow * 128 + ch) = *(uint4*)o8;
  }
}

// dual-output GEMM: out0 = A@W0, out1 = A@W1 (A read once)
__global__ __launch_bounds__(256, 2) void gemm64_2w(
    const u16* __restrict__ A, const u16* __restrict__ WT0, const u16* __restrict__ WT1,
    u16* __restrict__ out0, u16* __restrict__ out1, int M) {
  __shared__ u16 sO0[64][136];
  __shared__ u16 sO1[64][136];
  const int tid = threadIdx.x;
  const int wave = tid >> 6, lane = tid & 63;
  const int q = lane >> 4, l16 = lane & 15;
  const int m0 = blockIdx.x * 64;
  int arow = m0 + wave * 16 + l16;
  if (arow >= M) arow = M - 1;

  f32x4_t a0[8], a1[8];
#pragma unroll
  for (int b = 0; b < 8; ++b) {
    a0[b] = (f32x4_t){0.f, 0.f, 0.f, 0.f};
    a1[b] = (f32x4_t){0.f, 0.f, 0.f, 0.f};
  }
#pragma unroll 2
  for (int kk = 0; kk < 4; ++kk) {
    bf16x8_t af = *(const bf16x8_t*)(A + (size_t)arow * 128 + kk * 32 + q * 8);
#pragma unroll
    for (int nt = 0; nt < 8; ++nt) {
      bf16x8_t b0 = *(const bf16x8_t*)(WT0 + (size_t)(nt * 16 + l16) * 128 + kk * 32 + q * 8);
      bf16x8_t b1v = *(const bf16x8_t*)(WT1 + (size_t)(nt * 16 + l16) * 128 + kk * 32 + q * 8);
      a0[nt] = __builtin_amdgcn_mfma_f32_16x16x32_bf16(af, b0, a0[nt], 0, 0, 0);
      a1[nt] = __builtin_amdgcn_mfma_f32_16x16x32_bf16(af, b1v, a1[nt], 0, 0, 0);
    }
  }
  const int rowb = wave * 16 + q * 4;
#pragma unroll
  for (int r = 0; r < 4; ++r)
#pragma unroll
    for (int nt = 0; nt < 8; ++nt) {
      sO0[rowb + r][nt * 16 + l16] = fb(a0[nt][r]);
      sO1[rowb + r][nt * 16 + l16] = fb(a1[nt][r]);
    }
  __syncthreads();
#pragma unroll
  for (int it = 0; it < 4; ++it) {
    int lin = it * 256 + tid;
    int row = lin >> 4, ch = (lin & 15) * 8;
    int grow = m0 + row;
    if (grow >= M) continue;
    *(uint4*)(out0 + (size_t)grow * 128 + ch) = *(uint4*)(&sO0[row][ch]);
    *(uint4*)(out1 + (size_t)grow * 128 + ch) = *(uint4*)(&sO1[row][ch]);
  }
}

// ---------------- fused node-update kernel ----------------
// xh = LN(relu(aggr@WA + xh@WB + b1) @ W2 + b2) + xh   (in place, per 64-row tile)
__global__ __launch_bounds__(256, 2) void node_fused(
    u16* __restrict__ xh, const float* __restrict__ aggr, const u16* __restrict__ wtA,
    const u16* __restrict__ wtB, const float* __restrict__ b1, const u16* __restrict__ wt2,
    const float* __restrict__ b2, const float* __restrict__ gg, const float* __restrict__ bb,
    int M) {
  __shared__ u16 sH[64][136];
  const int tid = threadIdx.x;
  const int wave = tid >> 6, lane = tid & 63;
  const int q = lane >> 4, l16 = lane & 15;
  const int m0 = blockIdx.x * 64;
  const int rowb = wave * 16 + q * 4;
  int arow = m0 + wave * 16 + l16;
  int arc = arow < M ? arow : M - 1;

  bf16x8_t xf[4], af_[4];
#pragma unroll
  for (int kk = 0; kk < 4; ++kk) {
    xf[kk] = *(const bf16x8_t*)(xh + (size_t)arc * 128 + kk * 32 + q * 8);
    const float* ap = aggr + (size_t)arc * 128 + kk * 32 + q * 8;
    union { u16 u[8]; bf16x8_t v; } cv;
#pragma unroll
    for (int j = 0; j < 8; ++j) cv.u[j] = fb(ap[j]);
    af_[kk] = cv.v;
  }

  f32x4_t acc[8];
#pragma unroll
  for (int b = 0; b < 8; ++b) acc[b] = (f32x4_t){0.f, 0.f, 0.f, 0.f};
#pragma unroll
  for (int kk = 0; kk < 4; ++kk) {
#pragma unroll
    for (int nt = 0; nt < 8; ++nt) {
      bf16x8_t bA = *(const bf16x8_t*)(wtA + (size_t)(nt * 16 + l16) * 128 + kk * 32 + q * 8);
      bf16x8_t bB = *(const bf16x8_t*)(wtB + (size_t)(nt * 16 + l16) * 128 + kk * 32 + q * 8);
      acc[nt] = __builtin_amdgcn_mfma_f32_16x16x32_bf16(af_[kk], bA, acc[nt], 0, 0, 0);
      acc[nt] = __builtin_amdgcn_mfma_f32_16x16x32_bf16(xf[kk], bB, acc[nt], 0, 0, 0);
    }
  }
  float bcol1[8];
#pragma unroll
  for (int nt = 0; nt < 8; ++nt) bcol1[nt] = b1[nt * 16 + l16];
#pragma unroll
  for (int r = 0; r < 4; ++r)
#pragma unroll
    for (int nt = 0; nt < 8; ++nt) {
      float v = acc[nt][r] + bcol1[nt];
      sH[rowb + r][nt * 16 + l16] = fb(v > 0.f ? v : 0.f);
    }
  __syncthreads();

  f32x4_t acc2[8];
#pragma unroll
  for (int b = 0; b < 8; ++b) acc2[b] = (f32x4_t){0.f, 0.f, 0.f, 0.f};
#pragma unroll
  for (int kk = 0; kk < 4; ++kk) {
    bf16x8_t afm = *(const bf16x8_t*)(&sH[wave * 16 + l16][kk * 32 + q * 8]);
#pragma unroll
    for (int nt = 0; nt < 8; ++nt) {
      bf16x8_t bfv = *(const bf16x8_t*)(wt2 + (size_t)(nt * 16 + l16) * 128 + kk * 32 + q * 8);
      acc2[nt] = __builtin_amdgcn_mfma_f32_16x16x32_bf16(afm, bfv, acc2[nt], 0, 0, 0);
    }
  }
  float bcol[8], gcol[8], becol[8];
#pragma unroll
  for (int nt = 0; nt < 8; ++nt) {
    bcol[nt] = b2[nt * 16 + l16];
    gcol[nt] = gg[nt * 16 + l16];
    becol[nt] = bb[nt * 16 + l16];
  }
  float s[4] = {0, 0, 0, 0}, ss[4] = {0, 0, 0, 0};
#pragma unroll
  for (int r = 0; r < 4; ++r)
#pragma unroll
    for (int nt = 0; nt < 8; ++nt) {
      float v = acc2[nt][r] + bcol[nt];
      s[r] += v;
      ss[r] += v * v;
    }
#pragma unroll
  for (int r = 0; r < 4; ++r) {
#pragma unroll
    for (int m = 1; m <= 8; m <<= 1) {
      s[r] += __shfl_xor(s[r], m, 64);
      ss[r] += __shfl_xor(ss[r], m, 64);
    }
  }
  __syncthreads();
#pragma unroll
  for (int r = 0; r < 4; ++r) {
    float mean = s[r] * (1.f / 128.f);
    float var = fmaxf(ss[r] * (1.f / 128.f) - mean * mean, 0.f);
    float rstd = rsqrtf(var + 1e-5f);
#pragma unroll
    for (int nt = 0; nt < 8; ++nt) {
      float v = (acc2[nt][r] + bcol[nt] - mean) * rstd * gcol[nt] + becol[nt];
      sH[rowb + r][nt * 16 + l16] = fb(v);
    }
  }
  __syncthreads();
  if (arow < M) {
#pragma unroll
    for (int kk = 0; kk < 4; ++kk) {
      u16 y8[8];
      *(uint4*)y8 = *(uint4*)(&sH[wave * 16 + l16][kk * 32 + q * 8]);
#pragma unroll
      for (int j = 0; j < 8; ++j) y8[j] = fb(bl(y8[j]) + bl((u16)xf[kk][j]));
      *(uint4*)(xh + (size_t)arow * 128 + kk * 32 + q * 8) = *(uint4*)y8;
    }
  }
}

// ---------------- fused edge kernel: 4 independent waves, NO barriers ----------------
// Each wave owns 16 edges + its own LDS rows; all LDS deps are same-wave (in-order DS).
template <bool CSR>
__global__ __launch_bounds__(256, 2) void edge_fused(
    u16* __restrict__ eh, const u16* __restrict__ xhA, const u16* __restrict__ xhB,
    const u16* __restrict__ wtC, const float* __restrict__ b1, const u16* __restrict__ wt2,
    const float* __restrict__ b2, const float* __restrict__ gg, const float* __restrict__ bb,
    const int* __restrict__ sArr, const int* __restrict__ rArr,
    const int* __restrict__ startp, float* __restrict__ aggr, int E) {
  __shared__ u16 sHm[64][136];
  __shared__ u16 sHe[64][136];
  __shared__ int sS[64], sR[64];
  const int tid = threadIdx.x;
  const int wave = tid >> 6, lane = tid & 63;
  const int q = lane >> 4, l16 = lane & 15;
  const int m0 = blockIdx.x * 64;
  const int wbase = wave * 16;
  const int rowb = wbase + q * 4;
  int arow = m0 + wbase + l16;
  int arc = arow < E ? arow : E - 1;

  // wave-local index staging (read back only by this wave)
  if (lane < 16) {
    int e = m0 + wbase + lane;
    sS[wbase + lane] = (e < E) ? sArr[e] : 0;
    sR[wbase + lane] = (e < E) ? rArr[e] : -1;
  }

  // eh fragments in registers for GEMM1
  bf16x8_t ehf[4];
#pragma unroll
  for (int kk = 0; kk < 4; ++kk)
    ehf[kk] = *(const bf16x8_t*)(eh + (size_t)arc * 128 + kk * 32 + q * 8);

  // phase 1: T = eh @ WC
  f32x4_t accC[8];
#pragma unroll
  for (int b = 0; b < 8; ++b) accC[b] = (f32x4_t){0.f, 0.f, 0.f, 0.f};
#pragma unroll
  for (int kk = 0; kk < 4; ++kk) {
#pragma unroll
    for (int nt = 0; nt < 8; ++nt) {
      bf16x8_t bfv = *(const bf16x8_t*)(wtC + (size_t)(nt * 16 + l16) * 128 + kk * 32 + q * 8);
      accC[nt] = __builtin_amdgcn_mfma_f32_16x16x32_bf16(ehf[kk], bfv, accC[nt], 0, 0, 0);
    }
  }
#pragma unroll
  for (int r = 0; r < 4; ++r)
#pragma unroll
    for (int nt = 0; nt < 8; ++nt) sHm[rowb + r][nt * 16 + l16] = fb(accC[nt][r]);

  // phase 2: wave-local row-wise gather + ReLU -> H_msg, H_edge
  // lane covers row wbase+(lane>>2), chunks (lane&3)+it*4
  const int prow = wbase + (lane >> 2);
#pragma unroll
  for (int it = 0; it < 4; ++it) {
    int ch = ((lane & 3) + it * 4) * 8;
    int e = m0 + prow;
    bool ok = e < E;
    int s_ = sS[prow];
    int rr_ = sR[prow];
    int r_ = rr_ >= 0 ? rr_ : 0;
    u16 t8[8], ar[8], as_[8], br[8], bs[8], hm[8], he[8];
    *(uint4*)t8 = *(uint4*)(&sHm[prow][ch]);
    *(uint4*)ar = *(const uint4*)(xhA + (size_t)r_ * 128 + ch);
    *(uint4*)br = *(const uint4*)(xhB + (size_t)r_ * 128 + ch);
    *(uint4*)as_ = *(const uint4*)(xhA + (size_t)s_ * 128 + ch);
    *(uint4*)bs = *(const uint4*)(xhB + (size_t)s_ * 128 + ch);
#pragma unroll
    for (int j = 0; j < 8; ++j) {
      float t = bl(t8[j]) + b1[ch + j];
      float vm = t + bl(ar[j]) + bl(bs[j]);
      float ve = t + bl(as_[j]) + bl(br[j]);
      hm[j] = (ok && vm > 0.f) ? fb(vm) : 0;
      he[j] = (ok && ve > 0.f) ? fb(ve) : 0;
    }
    *(uint4*)(&sHm[prow][ch]) = *(uint4*)hm;
    *(uint4*)(&sHe[prow][ch]) = *(uint4*)he;
  }

  float bcol[8], gcol[8], becol[8];
#pragma unroll
  for (int nt = 0; nt < 8; ++nt) {
    bcol[nt] = b2[nt * 16 + l16];
    gcol[nt] = gg[nt * 16 + l16];
    becol[nt] = bb[nt * 16 + l16];
  }

  // phase 3: both GEMMs, LN stats (wave-local LDS reads)
  f32x4_t accM[8], accE[8];
#pragma unroll
  for (int b = 0; b < 8; ++b) {
    accM[b] = (f32x4_t){0.f, 0.f, 0.f, 0.f};
    accE[b] = (f32x4_t){0.f, 0.f, 0.f, 0.f};
  }
#pragma unroll
  for (int kk = 0; kk < 4; ++kk) {
    bf16x8_t afm = *(const bf16x8_t*)(&sHm[wbase + l16][kk * 32 + q * 8]);
    bf16x8_t afe = *(const bf16x8_t*)(&sHe[wbase + l16][kk * 32 + q * 8]);
#pragma unroll
    for (int nt = 0; nt < 8; ++nt) {
      bf16x8_t bfv = *(const bf16x8_t*)(wt2 + (size_t)(nt * 16 + l16) * 128 + kk * 32 + q * 8);
      accM[nt] = __builtin_amdgcn_mfma_f32_16x16x32_bf16(afm, bfv, accM[nt], 0, 0, 0);
      accE[nt] = __builtin_amdgcn_mfma_f32_16x16x32_bf16(afe, bfv, accE[nt], 0, 0, 0);
    }
  }
  float sm[4] = {0, 0, 0, 0}, ssm[4] = {0, 0, 0, 0};
  float se[4] = {0, 0, 0, 0}, sse[4] = {0, 0, 0, 0};
#pragma unroll
  for (int r = 0; r < 4; ++r)
#pragma unroll
    for (int nt = 0; nt < 8; ++nt) {
      float vm = accM[nt][r] + bcol[nt];
      float ve = accE[nt][r] + bcol[nt];
      sm[r] += vm; ssm[r] += vm * vm;
      se[r] += ve; sse[r] += ve * ve;
    }
#pragma unroll
  for (int r = 0; r < 4; ++r) {
#pragma unroll
    for (int m = 1; m <= 8; m <<= 1) {
      sm[r] += __shfl_xor(sm[r], m, 64);
      ssm[r] += __shfl_xor(ssm[r], m, 64);
      se[r] += __shfl_xor(se[r], m, 64);
      sse[r] += __shfl_xor(sse[r], m, 64);
    }
  }

  if (!CSR) {
#pragma unroll
    for (int r = 0; r < 4; ++r) {
      int row = m0 + rowb + r;
      if (row >= E) continue;
      int rr = sR[rowb + r];
      float mean = sm[r] * (1.f / 128.f);
      float var = fmaxf(ssm[r] * (1.f / 128.f) - mean * mean, 0.f);
      float rstd = rsqrtf(var + 1e-5f);
#pragma unroll
      for (int nt = 0; nt < 8; ++nt) {
        float v = (accM[nt][r] + bcol[nt] - mean) * rstd * gcol[nt] + becol[nt];
        atomicAdd(&aggr[(size_t)rr * 128 + nt * 16 + l16], v);
      }
    }
  }

  // stage LN'd Ym (CSR) and Ye back into own LDS rows (same-wave ordering)
#pragma unroll
  for (int r = 0; r < 4; ++r) {
    float meanE = se[r] * (1.f / 128.f);
    float varE = fmaxf(sse[r] * (1.f / 128.f) - meanE * meanE, 0.f);
    float rstdE = rsqrtf(varE + 1e-5f);
    float meanM = sm[r] * (1.f / 128.f);
    float varM = fmaxf(ssm[r] * (1.f / 128.f) - meanM * meanM, 0.f);
    float rstdM = rsqrtf(varM + 1e-5f);
#pragma unroll
    for (int nt = 0; nt < 8; ++nt) {
      float ve = (accE[nt][r] + bcol[nt] - meanE) * rstdE * gcol[nt] + becol[nt];
      sHe[rowb + r][nt * 16 + l16] = fb(ve);
      if (CSR) {
        float vm = (accM[nt][r] + bcol[nt] - meanM) * rstdM * gcol[nt] + becol[nt];
        sHm[rowb + r][nt * 16 + l16] = fb(vm);
      }
    }
  }

  // epilogue: wave-local row-wise eh residual+store; CSR: segmented aggregation
#pragma unroll
  for (int it = 0; it < 4; ++it) {
    int ch = ((lane & 3) + it * 4) * 8;
    int grow = m0 + prow;
    if (grow >= E) continue;
    u16 y8[8], e8[8];
    *(uint4*)y8 = *(uint4*)(&sHe[prow][ch]);
    *(uint4*)e8 = *(const uint4*)(eh + (size_t)grow * 128 + ch);
#pragma unroll
    for (int j = 0; j < 8; ++j) y8[j] = fb(bl(y8[j]) + bl(e8[j]));
    *(uint4*)(eh + (size_t)grow * 128 + ch) = *(uint4*)y8;

    if (CSR) {
      int rr = sR[prow];
      bool first = (prow == wbase) || (sR[prow - 1] != rr);
      if (!first) continue;
      int gs = startp[rr], ge2 = startp[rr + 1];
      int le = ge2 - m0;
      if (le > wbase + 16) le = wbase + 16;
      float acc[8] = {0, 0, 0, 0, 0, 0, 0, 0};
      for (int i = prow; i < le; ++i) {
        u16 m8[8];
        *(uint4*)m8 = *(uint4*)(&sHm[i][ch]);
#pragma unroll
        for (int j = 0; j < 8; ++j) acc[j] += bl(m8[j]);
      }
      if (gs >= m0 + wbase && ge2 <= m0 + wbase + 16) {
        *(float4*)(aggr + (size_t)rr * 128 + ch) = make_float4(acc[0], acc[1], acc[2], acc[3]);
        *(float4*)(aggr + (size_t)rr * 128 + ch + 4) =
            make_float4(acc[4], acc[5], acc[6], acc[7]);
      } else {
#pragma unroll
        for (int j = 0; j < 8; ++j) atomicAdd(&aggr[(size_t)rr * 128 + ch + j], acc[j]);
      }
    }
  }
}

// decoder: wave per node, 128->64 swish -> 64->5, times dt
__global__ void decoder_kernel(const u16* __restrict__ xh, const float* __restrict__ w1,
                               const float* __restrict__ b1, const float* __restrict__ w2,
                               const float* __restrict__ b2, float* __restrict__ out,
                               int n_nodes) {
  __shared__ float sx[4][128];
  int tid = threadIdx.x;
  int lw = tid >> 6, lane = tid & 63;
  int n0 = blockIdx.x * 4;
  for (int i = tid; i < 512; i += 256) {
    int nn = i >> 7, c = i & 127;
    int n = n0 + nn;
    sx[nn][c] = (n < n_nodes) ? bl(xh[(size_t)n * 128 + c]) : 0.f;
  }
  __syncthreads();
  int n = n0 + lw;
  float h = b1[lane];
#pragma unroll 16
  for (int k = 0; k < 128; ++k) h += sx[lw][k] * w1[k * 64 + lane];
  float hs = h * (1.f / (1.f + __expf(-h)));
  float d[5];
#pragma unroll
  for (int t = 0; t < 5; ++t) {
    float p = hs * w2[lane * 5 + t];
#pragma unroll
    for (int m = 1; m <= 32; m <<= 1) p += __shfl_xor(p, m, 64);
    d[t] = p;
  }
  if (lane == 0 && n < n_nodes) {
#pragma unroll
    for (int t = 0; t < 5; ++t)
      out[(size_t)n * 5 + t] = (float)(t + 1) * (d[t] + b2[t]);
  }
}

extern "C" void kernel_launch(void* const* d_in, const int* in_sizes, int n_in, void* d_out,
                              int out_size, void* d_ws, size_t ws_size, hipStream_t stream) {
  auto F = [&](int i) { return (const float*)d_in[i]; };
  const int* edge_index = (const int*)d_in[6];
  const int N_ = in_sizes[0];
  const int E_ = in_sizes[6] / 2;

  char* wsb = (char*)d_ws;
  size_t off = 0;
  auto alloc = [&](size_t bytes) -> char* {
    char* p = wsb + off;
    off += (bytes + 255) & ~(size_t)255;
    return p;
  };
  u16* xh = (u16*)alloc((size_t)N_ * 128 * 2);
  u16* xhA = (u16*)alloc((size_t)N_ * 128 * 2);
  u16* xhB = (u16*)alloc((size_t)N_ * 128 * 2);
  u16* h1n = (u16*)alloc((size_t)N_ * 128 * 2);
  u16* ehP = (u16*)alloc((size_t)E_ * 128 * 2);
  float* aggr = (float*)alloc((size_t)N_ * 128 * 4);
  float* nfeat = (float*)xhA;  // alias (dead before xhA live)
  float* efeat = (float*)xhB;  // alias
  u16* wne2T = (u16*)alloc(16384 * 2);
  u16* wee2T = (u16*)alloc(16384 * 2);
  u16* wpe1T = (u16*)alloc((size_t)9 * 16384 * 2);
  u16* wpe2T = (u16*)alloc((size_t)3 * 16384 * 2);
  u16* wpn1T = (u16*)alloc((size_t)6 * 16384 * 2);
  u16* wpn2T = (u16*)alloc((size_t)3 * 16384 * 2);

  const size_t base_off = off;
  int* startp = (int*)alloc((size_t)(N_ + 1) * 4);
  int* cntp = (int*)alloc((size_t)N_ * 4);
  int* partp = (int*)alloc((size_t)N_ * 4);
  int* bsump = (int*)alloc(((size_t)(N_ + 255) / 256) * 4 + 256);
  int* sortedS = (int*)alloc((size_t)E_ * 4);
  int* sortedR = (int*)alloc((size_t)E_ * 4);
  bool useCSR = (off <= ws_size);
  if (!useCSR) {
    off = base_off;
    if (off > ws_size) {
      sentinel_kernel<<<(out_size + 255) / 256, 256, 0, stream>>>((float*)d_out, out_size);
      return;
    }
  }

  TArgs ta;
  int ts = 0;
  ta.s[ts++] = {F(13), wne2T};
  ta.s[ts++] = {F(19), wee2T};
  for (int i = 0; i < 3; ++i)
    for (int b = 0; b < 3; ++b)
      ta.s[ts++] = {F(23) + (size_t)(i * 3 + b) * 16384, wpe1T + (size_t)(i * 3 + b) * 16384};
  for (int i = 0; i < 3; ++i) ta.s[ts++] = {F(25) + (size_t)i * 16384, wpe2T + (size_t)i * 16384};
  for (int i = 0; i < 3; ++i)
    for (int b = 0; b < 2; ++b)
      ta.s[ts++] = {F(29) + (size_t)(i * 2 + b) * 16384, wpn1T + (size_t)(i * 2 + b) * 16384};
  for (int i = 0; i < 3; ++i) ta.s[ts++] = {F(31) + (size_t)i * 16384, wpn2T + (size_t)i * 16384};

  const int tilesN = (N_ + 63) / 64;
  const int tilesE = (E_ + 63) / 64;
  const int nb = (N_ + 255) / 256;
  dim3 blk(256);

  transpose_w<<<23, blk, 0, stream>>>(ta);

  const int* sArr = edge_index;
  const int* rArr = edge_index + E_;
  if (useCSR) {
    zero_i32<<<(N_ + 255) / 256, blk, 0, stream>>>(cntp, N_);
    deg_count<<<(E_ + 255) / 256, blk, 0, stream>>>(edge_index, cntp, E_);
    scan1<<<nb, blk, 0, stream>>>(cntp, partp, bsump, N_);
    scan2<<<1, blk, 0, stream>>>(bsump, nb);
    scan3<<<nb, blk, 0, stream>>>(partp, bsump, startp, N_);
    zero_i32<<<(N_ + 255) / 256, blk, 0, stream>>>(cntp, N_);
    fill_slot<<<(E_ + 255) / 256, blk, 0, stream>>>(edge_index, cntp, startp, sortedS, sortedR,
                                                    E_);
    sArr = sortedS;
    rArr = sortedR;
  }

  // ---- encode ----
  node_feat_kernel<<<(N_ + 255) / 256, blk, 0, stream>>>(F(0), F(1), F(2), F(3), F(4), F(7),
                                                         F(8), nfeat, N_);
  enc1_kernel<9><<<(N_ * 128 + 255) / 256, blk, 0, stream>>>(nfeat, F(11), F(12), h1n, N_);
  gemm64<GM_LN, false, false><<<tilesN, blk, 0, stream>>>(h1n, wne2T, nullptr, nullptr, F(14),
                                                          F(15), F(16), nullptr, xh, N_);
  edge_feat_kernel<<<(E_ + 255) / 256, blk, 0, stream>>>(sArr, rArr, F(5), F(0), F(9), F(10),
                                                         efeat, E_);
  enc1_kernel<4><<<(E_ * 128 + 255) / 256, blk, 0, stream>>>(efeat, F(17), F(18), ehP, E_);
  gemm64<GM_LN, false, false><<<tilesE, blk, 0, stream>>>(ehP, wee2T, nullptr, nullptr, F(20),
                                                          F(21), F(22), nullptr, ehP, E_);

  // ---- process steps ----
  for (int i = 0; i < 3; ++i) {
    const u16* wtA = wpe1T + (size_t)(i * 3 + 0) * 16384;
    const u16* wtB = wpe1T + (size_t)(i * 3 + 1) * 16384;
    const u16* wtC = wpe1T + (size_t)(i * 3 + 2) * 16384;
    const float* pb1 = F(24) + i * 128;
    const u16* wt2 = wpe2T + (size_t)i * 16384;
    const float* pb2 = F(26) + i * 128;
    const float* pg = F(27) + i * 128;
    const float* pbe = F(28) + i * 128;
    const u16* wtnA = wpn1T + (size_t)(i * 2 + 0) * 16384;
    const u16* wtnB = wpn1T + (size_t)(i * 2 + 1) * 16384;
    const float* nb1 = F(30) + i * 128;
    const u16* wtn2 = wpn2T + (size_t)i * 16384;
    const float* nb2 = F(32) + i * 128;
    const float* ng = F(33) + i * 128;
    const float* nbe = F(34) + i * 128;

    gemm64_2w<<<tilesN, blk, 0, stream>>>(xh, wtA, wtB, xhA, xhB, N_);
    (void)hipMemsetAsync(aggr, 0, (size_t)N_ * 128 * 4, stream);
    if (useCSR) {
      edge_fused<true><<<tilesE, blk, 0, stream>>>(ehP, xhA, xhB, wtC, pb1, wt2, pb2, pg, pbe,
                                                   sArr, rArr, startp, aggr, E_);
    } else {
      edge_fused<false><<<tilesE, blk, 0, stream>>>(ehP, xhA, xhB, wtC, pb1, wt2, pb2, pg, pbe,
                                                    sArr, rArr, nullptr, aggr, E_);
    }
    node_fused<<<tilesN, blk, 0, stream>>>(xh, aggr, wtnA, wtnB, nb1, wtn2, nb2, ng, nbe, N_);
  }

  // ---- decode ----
  decoder_kernel<<<(N_ + 3) / 4, blk, 0, stream>>>(xh, F(35), F(36), F(37), F(38),
                                                   (float*)d_out, N_);
}

// Round 16
// 1313.151 us; speedup vs baseline: 1.1587x; 1.1587x over previous
//
#include <hip/hip_runtime.h>
#include <stdint.h>

typedef unsigned short u16;
typedef __attribute__((ext_vector_type(8))) short bf16x8_t;
typedef __attribute__((ext_vector_type(4))) float f32x4_t;

__device__ __forceinline__ float bl(u16 x) {
  union { unsigned u; float f; } c; c.u = ((unsigned)x) << 16; return c.f;
}
__device__ __forceinline__ u16 fb(float x) {
  union { float f; unsigned u; } c; c.f = x;
  unsigned r = c.u + 0x7fffu + ((c.u >> 16) & 1u);
  return (u16)(r >> 16);
}

__global__ void sentinel_kernel(float* out, int n) {
  int i = blockIdx.x * 256 + threadIdx.x;
  if (i < n) out[i] = 12345.f;
}

// ---------------- weight transpose: wT[n][k] = fb(W[k][n]) ----------------
struct TSeg { const float* src; u16* dst; };
struct TArgs { TSeg s[23]; };
__global__ void transpose_w(TArgs a) {
  const float* src = a.s[blockIdx.x].src;
  u16* dst = a.s[blockIdx.x].dst;
  for (int e = threadIdx.x; e < 16384; e += 256) {
    int n = e >> 7, k = e & 127;
    dst[e] = fb(src[k * 128 + n]);
  }
}

// ---------------- CSR build + receiver-sort ----------------
__global__ void zero_i32(int* p, int n) {
  int i = blockIdx.x * 256 + threadIdx.x;
  if (i < n) p[i] = 0;
}
__global__ void deg_count(const int* __restrict__ ei, int* __restrict__ cnt, int E) {
  int e = blockIdx.x * 256 + threadIdx.x;
  if (e < E) atomicAdd(&cnt[ei[E + e]], 1);
}
__global__ void scan1(const int* __restrict__ cnt, int* __restrict__ part,
                      int* __restrict__ bsum, int N) {
  __shared__ int s[256];
  int i = blockIdx.x * 256 + threadIdx.x;
  s[threadIdx.x] = (i < N) ? cnt[i] : 0;
  __syncthreads();
#pragma unroll
  for (int o = 1; o < 256; o <<= 1) {
    int t = (threadIdx.x >= o) ? s[threadIdx.x - o] : 0;
    __syncthreads();
    s[threadIdx.x] += t;
    __syncthreads();
  }
  if (i < N) part[i] = s[threadIdx.x];
  if (threadIdx.x == 255) bsum[blockIdx.x] = s[255];
}
__global__ void scan2(int* bsum, int nb) {
  if (threadIdx.x == 0 && blockIdx.x == 0) {
    int acc = 0;
    for (int i = 0; i < nb; ++i) { int t = bsum[i]; bsum[i] = acc; acc += t; }
  }
}
__global__ void scan3(const int* __restrict__ part, const int* __restrict__ bsum,
                      int* __restrict__ start, int N) {
  int i = blockIdx.x * 256 + threadIdx.x;
  if (i < N) start[i + 1] = part[i] + bsum[i >> 8];
  if (i == 0) start[0] = 0;
}
__global__ void fill_slot(const int* __restrict__ ei, int* __restrict__ cnt2,
                          const int* __restrict__ start, int* __restrict__ sortedS,
                          int* __restrict__ sortedR, int E) {
  int e = blockIdx.x * 256 + threadIdx.x;
  if (e >= E) return;
  int s = ei[e], r = ei[E + e];
  int p = atomicAdd(&cnt2[r], 1);
  int slot = start[r] + p;
  sortedS[slot] = s;
  sortedR[slot] = r;
}

// ---------------- feature kernels ----------------
__global__ void node_feat_kernel(const float* __restrict__ t, const float* __restrict__ tp,
                                 const float* __restrict__ q, const float* __restrict__ qp,
                                 const float* __restrict__ qn, const float* __restrict__ nm,
                                 const float* __restrict__ ns, float* __restrict__ nfeat,
                                 int n_nodes) {
  int n = blockIdx.x * 256 + threadIdx.x;
  if (n >= n_nodes) return;
  float u = t[n];
  float x[9];
  x[0] = u; x[1] = u - tp[n];
  float hq = q[n];
  x[2] = hq; x[3] = hq - qp[n];
#pragma unroll
  for (int j = 0; j < 5; ++j) x[4 + j] = qn[n * 5 + j];
#pragma unroll
  for (int k = 0; k < 9; ++k) nfeat[n * 9 + k] = (x[k] - nm[k]) / ns[k];
}

__global__ void edge_feat_kernel(const int* __restrict__ sArr, const int* __restrict__ rArr,
                                 const float* __restrict__ mp, const float* __restrict__ u,
                                 const float* __restrict__ em, const float* __restrict__ es,
                                 float* __restrict__ efeat, int n_edges) {
  int e = blockIdx.x * 256 + threadIdx.x;
  if (e >= n_edges) return;
  int s = sArr[e], r = rArr[e];
  float rx = mp[s * 2] - mp[r * 2];
  float ry = mp[s * 2 + 1] - mp[r * 2 + 1];
  float d = sqrtf(rx * rx + ry * ry);
  float rt = u[s] - u[r];
  float x[4] = {rx, ry, d, rt};
#pragma unroll
  for (int k = 0; k < 4; ++k) efeat[e * 4 + k] = (x[k] - em[k]) / es[k];
}

template <int K>
__global__ void enc1_kernel(const float* __restrict__ feat, const float* __restrict__ w1,
                            const float* __restrict__ b1, u16* __restrict__ out, int M) {
  int gid = blockIdx.x * 256 + threadIdx.x;
  int n = gid >> 7, h = gid & 127;
  if (n >= M) return;
  float acc = b1[h];
#pragma unroll
  for (int k = 0; k < K; ++k) acc += feat[n * K + k] * w1[k * 128 + h];
  out[n * 128 + h] = fb(acc > 0.f ? acc : 0.f);
}

// ---------------- LDS-free-GEMM + LDS-staged vector-store epilogue ----------------
#define GM_NONE 0
#define GM_RELU 1
#define GM_LN 2

template <int MODE, bool DUAL, bool A0F32>
__global__ __launch_bounds__(256, 2) void gemm64(
    const void* __restrict__ A0v, const u16* __restrict__ WT0, const u16* __restrict__ A1,
    const u16* __restrict__ WT1, const float* __restrict__ bias, const float* __restrict__ gg,
    const float* __restrict__ bb, const u16* __restrict__ resid, u16* __restrict__ out, int M) {
  __shared__ u16 sO[64][136];
  const int tid = threadIdx.x;
  const int wave = tid >> 6, lane = tid & 63;
  const int q = lane >> 4, l16 = lane & 15;
  const int m0 = blockIdx.x * 64;
  int arow = m0 + wave * 16 + l16;
  if (arow >= M) arow = M - 1;

  f32x4_t acc[8];
#pragma unroll
  for (int b = 0; b < 8; ++b) acc[b] = (f32x4_t){0.f, 0.f, 0.f, 0.f};

  const int NKT = DUAL ? 2 : 1;
#pragma unroll 1
  for (int kt = 0; kt < NKT; ++kt) {
    const u16* WT = kt ? WT1 : WT0;
#pragma unroll
    for (int kk = 0; kk < 4; ++kk) {
      bf16x8_t af;
      if (A0F32 && kt == 0) {
        const float* ap = (const float*)A0v + (size_t)arow * 128 + kk * 32 + q * 8;
        union { u16 u[8]; bf16x8_t v; } cv;
#pragma unroll
        for (int j = 0; j < 8; ++j) cv.u[j] = fb(ap[j]);
        af = cv.v;
      } else {
        const u16* ap = (kt ? A1 : (const u16*)A0v) + (size_t)arow * 128 + kk * 32 + q * 8;
        af = *(const bf16x8_t*)ap;
      }
      const u16* wp = WT + kk * 32 + q * 8;
#pragma unroll
      for (int nt = 0; nt < 8; ++nt) {
        bf16x8_t bfv = *(const bf16x8_t*)(wp + (size_t)(nt * 16 + l16) * 128);
        acc[nt] = __builtin_amdgcn_mfma_f32_16x16x32_bf16(af, bfv, acc[nt], 0, 0, 0);
      }
    }
  }

  const int rowb = wave * 16 + q * 4;
  if (MODE == GM_NONE) {
#pragma unroll
    for (int r = 0; r < 4; ++r)
#pragma unroll
      for (int nt = 0; nt < 8; ++nt) sO[rowb + r][nt * 16 + l16] = fb(acc[nt][r]);
  } else if (MODE == GM_RELU) {
    float bcol[8];
#pragma unroll
    for (int nt = 0; nt < 8; ++nt) bcol[nt] = bias[nt * 16 + l16];
#pragma unroll
    for (int r = 0; r < 4; ++r)
#pragma unroll
      for (int nt = 0; nt < 8; ++nt) {
        float v = acc[nt][r] + bcol[nt];
        sO[rowb + r][nt * 16 + l16] = fb(v > 0.f ? v : 0.f);
      }
  } else {
    float bcol[8], gcol[8], becol[8];
#pragma unroll
    for (int nt = 0; nt < 8; ++nt) {
      bcol[nt] = bias[nt * 16 + l16];
      gcol[nt] = gg[nt * 16 + l16];
      becol[nt] = bb[nt * 16 + l16];
    }
    float s[4] = {0, 0, 0, 0}, ss[4] = {0, 0, 0, 0};
#pragma unroll
    for (int r = 0; r < 4; ++r)
#pragma unroll
      for (int nt = 0; nt < 8; ++nt) {
        float v = acc[nt][r] + bcol[nt];
        s[r] += v;
        ss[r] += v * v;
      }
#pragma unroll
    for (int r = 0; r < 4; ++r) {
#pragma unroll
      for (int m = 1; m <= 8; m <<= 1) {
        s[r] += __shfl_xor(s[r], m, 64);
        ss[r] += __shfl_xor(ss[r], m, 64);
      }
    }
#pragma unroll
    for (int r = 0; r < 4; ++r) {
      float mean = s[r] * (1.f / 128.f);
      float var = fmaxf(ss[r] * (1.f / 128.f) - mean * mean, 0.f);
      float rstd = rsqrtf(var + 1e-5f);
#pragma unroll
      for (int nt = 0; nt < 8; ++nt) {
        float v = (acc[nt][r] + bcol[nt] - mean) * rstd * gcol[nt] + becol[nt];
        sO[rowb + r][nt * 16 + l16] = fb(v);
      }
    }
  }
  __syncthreads();
#pragma unroll
  for (int it = 0; it < 4; ++it) {
    int lin = it * 256 + tid;
    int row = lin >> 4, ch = (lin & 15) * 8;
    int grow = m0 + row;
    if (grow >= M) continue;
    u16 o8[8];
    *(uint4*)o8 = *(uint4*)(&sO[row][ch]);
    if (MODE == GM_LN && resid) {
      u16 r8[8];
      *(uint4*)r8 = *(const uint4*)(resid + (size_t)grow * 128 + ch);
#pragma unroll
      for (int j = 0; j < 8; ++j) o8[j] = fb(bl(o8[j]) + bl(r8[j]));
    }
    *(uint4*)(out + (size_t)grow * 128 + ch) = *(uint4*)o8;
  }
}

// dual-output GEMM: out0 = A@W0, out1 = A@W1 (A read once); also zeroes aggr rows
__global__ __launch_bounds__(256, 2) void gemm64_2w(
    const u16* __restrict__ A, const u16* __restrict__ WT0, const u16* __restrict__ WT1,
    u16* __restrict__ out0, u16* __restrict__ out1, float* __restrict__ aggr, int M) {
  __shared__ u16 sO0[64][136];
  __shared__ u16 sO1[64][136];
  const int tid = threadIdx.x;
  const int wave = tid >> 6, lane = tid & 63;
  const int q = lane >> 4, l16 = lane & 15;
  const int m0 = blockIdx.x * 64;
  int arow = m0 + wave * 16 + l16;
  if (arow >= M) arow = M - 1;

  // zero this block's aggr rows (64 rows x 128 f32), overlapped with GEMM
  {
    float4 z = make_float4(0.f, 0.f, 0.f, 0.f);
#pragma unroll
    for (int it = 0; it < 8; ++it) {
      int lin = it * 256 + tid;           // 2048 float4 slots
      int row = lin >> 5, c4 = (lin & 31) * 4;
      int grow = m0 + row;
      if (grow < M) *(float4*)(aggr + (size_t)grow * 128 + c4) = z;
    }
  }

  f32x4_t a0[8], a1[8];
#pragma unroll
  for (int b = 0; b < 8; ++b) {
    a0[b] = (f32x4_t){0.f, 0.f, 0.f, 0.f};
    a1[b] = (f32x4_t){0.f, 0.f, 0.f, 0.f};
  }
#pragma unroll 2
  for (int kk = 0; kk < 4; ++kk) {
    bf16x8_t af = *(const bf16x8_t*)(A + (size_t)arow * 128 + kk * 32 + q * 8);
#pragma unroll
    for (int nt = 0; nt < 8; ++nt) {
      bf16x8_t b0 = *(const bf16x8_t*)(WT0 + (size_t)(nt * 16 + l16) * 128 + kk * 32 + q * 8);
      bf16x8_t b1v = *(const bf16x8_t*)(WT1 + (size_t)(nt * 16 + l16) * 128 + kk * 32 + q * 8);
      a0[nt] = __builtin_amdgcn_mfma_f32_16x16x32_bf16(af, b0, a0[nt], 0, 0, 0);
      a1[nt] = __builtin_amdgcn_mfma_f32_16x16x32_bf16(af, b1v, a1[nt], 0, 0, 0);
    }
  }
  const int rowb = wave * 16 + q * 4;
#pragma unroll
  for (int r = 0; r < 4; ++r)
#pragma unroll
    for (int nt = 0; nt < 8; ++nt) {
      sO0[rowb + r][nt * 16 + l16] = fb(a0[nt][r]);
      sO1[rowb + r][nt * 16 + l16] = fb(a1[nt][r]);
    }
  __syncthreads();
#pragma unroll
  for (int it = 0; it < 4; ++it) {
    int lin = it * 256 + tid;
    int row = lin >> 4, ch = (lin & 15) * 8;
    int grow = m0 + row;
    if (grow >= M) continue;
    *(uint4*)(out0 + (size_t)grow * 128 + ch) = *(uint4*)(&sO0[row][ch]);
    *(uint4*)(out1 + (size_t)grow * 128 + ch) = *(uint4*)(&sO1[row][ch]);
  }
}

// ---------------- fused node-update kernel ----------------
// xh = LN(relu(aggr@WA + xh@WB + b1) @ W2 + b2) + xh   (in place, per 64-row tile)
__global__ __launch_bounds__(256, 2) void node_fused(
    u16* __restrict__ xh, const float* __restrict__ aggr, const u16* __restrict__ wtA,
    const u16* __restrict__ wtB, const float* __restrict__ b1, const u16* __restrict__ wt2,
    const float* __restrict__ b2, const float* __restrict__ gg, const float* __restrict__ bb,
    int M) {
  __shared__ u16 sH[64][136];
  const int tid = threadIdx.x;
  const int wave = tid >> 6, lane = tid & 63;
  const int q = lane >> 4, l16 = lane & 15;
  const int m0 = blockIdx.x * 64;
  const int rowb = wave * 16 + q * 4;
  int arow = m0 + wave * 16 + l16;
  int arc = arow < M ? arow : M - 1;

  bf16x8_t xf[4], af_[4];
#pragma unroll
  for (int kk = 0; kk < 4; ++kk) {
    xf[kk] = *(const bf16x8_t*)(xh + (size_t)arc * 128 + kk * 32 + q * 8);
    const float* ap = aggr + (size_t)arc * 128 + kk * 32 + q * 8;
    union { u16 u[8]; bf16x8_t v; } cv;
#pragma unroll
    for (int j = 0; j < 8; ++j) cv.u[j] = fb(ap[j]);
    af_[kk] = cv.v;
  }

  f32x4_t acc[8];
#pragma unroll
  for (int b = 0; b < 8; ++b) acc[b] = (f32x4_t){0.f, 0.f, 0.f, 0.f};
#pragma unroll
  for (int kk = 0; kk < 4; ++kk) {
#pragma unroll
    for (int nt = 0; nt < 8; ++nt) {
      bf16x8_t bA = *(const bf16x8_t*)(wtA + (size_t)(nt * 16 + l16) * 128 + kk * 32 + q * 8);
      bf16x8_t bB = *(const bf16x8_t*)(wtB + (size_t)(nt * 16 + l16) * 128 + kk * 32 + q * 8);
      acc[nt] = __builtin_amdgcn_mfma_f32_16x16x32_bf16(af_[kk], bA, acc[nt], 0, 0, 0);
      acc[nt] = __builtin_amdgcn_mfma_f32_16x16x32_bf16(xf[kk], bB, acc[nt], 0, 0, 0);
    }
  }
  float bcol1[8];
#pragma unroll
  for (int nt = 0; nt < 8; ++nt) bcol1[nt] = b1[nt * 16 + l16];
#pragma unroll
  for (int r = 0; r < 4; ++r)
#pragma unroll
    for (int nt = 0; nt < 8; ++nt) {
      float v = acc[nt][r] + bcol1[nt];
      sH[rowb + r][nt * 16 + l16] = fb(v > 0.f ? v : 0.f);
    }
  __syncthreads();

  f32x4_t acc2[8];
#pragma unroll
  for (int b = 0; b < 8; ++b) acc2[b] = (f32x4_t){0.f, 0.f, 0.f, 0.f};
#pragma unroll
  for (int kk = 0; kk < 4; ++kk) {
    bf16x8_t afm = *(const bf16x8_t*)(&sH[wave * 16 + l16][kk * 32 + q * 8]);
#pragma unroll
    for (int nt = 0; nt < 8; ++nt) {
      bf16x8_t bfv = *(const bf16x8_t*)(wt2 + (size_t)(nt * 16 + l16) * 128 + kk * 32 + q * 8);
      acc2[nt] = __builtin_amdgcn_mfma_f32_16x16x32_bf16(afm, bfv, acc2[nt], 0, 0, 0);
    }
  }
  float bcol[8], gcol[8], becol[8];
#pragma unroll
  for (int nt = 0; nt < 8; ++nt) {
    bcol[nt] = b2[nt * 16 + l16];
    gcol[nt] = gg[nt * 16 + l16];
    becol[nt] = bb[nt * 16 + l16];
  }
  float s[4] = {0, 0, 0, 0}, ss[4] = {0, 0, 0, 0};
#pragma unroll
  for (int r = 0; r < 4; ++r)
#pragma unroll
    for (int nt = 0; nt < 8; ++nt) {
      float v = acc2[nt][r] + bcol[nt];
      s[r] += v;
      ss[r] += v * v;
    }
#pragma unroll
  for (int r = 0; r < 4; ++r) {
#pragma unroll
    for (int m = 1; m <= 8; m <<= 1) {
      s[r] += __shfl_xor(s[r], m, 64);
      ss[r] += __shfl_xor(ss[r], m, 64);
    }
  }
  __syncthreads();
#pragma unroll
  for (int r = 0; r < 4; ++r) {
    float mean = s[r] * (1.f / 128.f);
    float var = fmaxf(ss[r] * (1.f / 128.f) - mean * mean, 0.f);
    float rstd = rsqrtf(var + 1e-5f);
#pragma unroll
    for (int nt = 0; nt < 8; ++nt) {
      float v = (acc2[nt][r] + bcol[nt] - mean) * rstd * gcol[nt] + becol[nt];
      sH[rowb + r][nt * 16 + l16] = fb(v);
    }
  }
  __syncthreads();
  if (arow < M) {
#pragma unroll
    for (int kk = 0; kk < 4; ++kk) {
      u16 y8[8];
      *(uint4*)y8 = *(uint4*)(&sH[wave * 16 + l16][kk * 32 + q * 8]);
#pragma unroll
      for (int j = 0; j < 8; ++j) y8[j] = fb(bl(y8[j]) + bl((u16)xf[kk][j]));
      *(uint4*)(xh + (size_t)arow * 128 + kk * 32 + q * 8) = *(uint4*)y8;
    }
  }
}

// ---------------- fused edge kernel (round-12 champion) ----------------
template <bool CSR>
__global__ __launch_bounds__(256, 2) void edge_fused(
    u16* __restrict__ eh, const u16* __restrict__ xhA, const u16* __restrict__ xhB,
    const u16* __restrict__ wtC, const float* __restrict__ b1, const u16* __restrict__ wt2,
    const float* __restrict__ b2, const float* __restrict__ gg, const float* __restrict__ bb,
    const int* __restrict__ sArr, const int* __restrict__ rArr,
    const int* __restrict__ startp, float* __restrict__ aggr, int E) {
  __shared__ u16 sHm[64][136];
  __shared__ u16 sHe[64][136];
  __shared__ int sR[64];
  const int tid = threadIdx.x;
  const int wave = tid >> 6, lane = tid & 63;
  const int q = lane >> 4, l16 = lane & 15;
  const int m0 = blockIdx.x * 64;
  const int rowb = wave * 16 + q * 4;
  int arow = m0 + wave * 16 + l16;
  int arc = arow < E ? arow : E - 1;

  if (tid < 64) {
    int e = m0 + tid;
    sR[tid] = (e < E) ? rArr[e] : -1;
  }

  // prefetch sender gather rows (random-latency; independent of T GEMM)
  int prow[4], pch[4], pr_[4];
  uint4 pAs[4], pBs[4];
#pragma unroll
  for (int it = 0; it < 4; ++it) {
    int lin = it * 256 + tid;
    prow[it] = lin >> 4;
    pch[it] = (lin & 15) * 8;
    int ge = m0 + prow[it];
    int gc = ge < E ? ge : E - 1;
    int ps = sArr[gc];
    pr_[it] = rArr[gc];
    pAs[it] = *(const uint4*)(xhA + (size_t)ps * 128 + pch[it]);
    pBs[it] = *(const uint4*)(xhB + (size_t)ps * 128 + pch[it]);
  }
  // eh fragments kept in registers (phase-1 GEMM)
  bf16x8_t ehf[4];
#pragma unroll
  for (int kk = 0; kk < 4; ++kk)
    ehf[kk] = *(const bf16x8_t*)(eh + (size_t)arc * 128 + kk * 32 + q * 8);

  // phase 1: T = eh @ WC
  f32x4_t accC[8];
#pragma unroll
  for (int b = 0; b < 8; ++b) accC[b] = (f32x4_t){0.f, 0.f, 0.f, 0.f};
#pragma unroll
  for (int kk = 0; kk < 4; ++kk) {
#pragma unroll
    for (int nt = 0; nt < 8; ++nt) {
      bf16x8_t bfv = *(const bf16x8_t*)(wtC + (size_t)(nt * 16 + l16) * 128 + kk * 32 + q * 8);
      accC[nt] = __builtin_amdgcn_mfma_f32_16x16x32_bf16(ehf[kk], bfv, accC[nt], 0, 0, 0);
    }
  }
#pragma unroll
  for (int r = 0; r < 4; ++r)
#pragma unroll
    for (int nt = 0; nt < 8; ++nt) sHm[rowb + r][nt * 16 + l16] = fb(accC[nt][r]);
  __syncthreads();

  // phase 2: receiver rows (sorted -> cache-friendly) + prefetched sender rows
#pragma unroll
  for (int it = 0; it < 4; ++it) {
    int row = prow[it], ch = pch[it];
    bool ok = (m0 + row) < E;
    int r_ = pr_[it] >= 0 ? pr_[it] : 0;
    u16 t8[8], ar[8], as_[8], br[8], bs[8], hm[8], he[8];
    *(uint4*)t8 = *(uint4*)(&sHm[row][ch]);
    *(uint4*)ar = *(const uint4*)(xhA + (size_t)r_ * 128 + ch);
    *(uint4*)br = *(const uint4*)(xhB + (size_t)r_ * 128 + ch);
    *(uint4*)as_ = pAs[it];
    *(uint4*)bs = pBs[it];
#pragma unroll
    for (int j = 0; j < 8; ++j) {
      float t = bl(t8[j]) + b1[ch + j];
      float vm = t + bl(ar[j]) + bl(bs[j]);
      float ve = t + bl(as_[j]) + bl(br[j]);
      hm[j] = (ok && vm > 0.f) ? fb(vm) : 0;
      he[j] = (ok && ve > 0.f) ? fb(ve) : 0;
    }
    *(uint4*)(&sHm[row][ch]) = *(uint4*)hm;
    *(uint4*)(&sHe[row][ch]) = *(uint4*)he;
  }
  __syncthreads();

  float bcol[8], gcol[8], becol[8];
#pragma unroll
  for (int nt = 0; nt < 8; ++nt) {
    bcol[nt] = b2[nt * 16 + l16];
    gcol[nt] = gg[nt * 16 + l16];
    becol[nt] = bb[nt * 16 + l16];
  }

  // phase 3: both GEMMs back-to-back, then LN stats
  f32x4_t accM[8], accE[8];
#pragma unroll
  for (int b = 0; b < 8; ++b) {
    accM[b] = (f32x4_t){0.f, 0.f, 0.f, 0.f};
    accE[b] = (f32x4_t){0.f, 0.f, 0.f, 0.f};
  }
#pragma unroll
  for (int kk = 0; kk < 4; ++kk) {
    bf16x8_t afm = *(const bf16x8_t*)(&sHm[wave * 16 + l16][kk * 32 + q * 8]);
    bf16x8_t afe = *(const bf16x8_t*)(&sHe[wave * 16 + l16][kk * 32 + q * 8]);
#pragma unroll
    for (int nt = 0; nt < 8; ++nt) {
      bf16x8_t bfv = *(const bf16x8_t*)(wt2 + (size_t)(nt * 16 + l16) * 128 + kk * 32 + q * 8);
      accM[nt] = __builtin_amdgcn_mfma_f32_16x16x32_bf16(afm, bfv, accM[nt], 0, 0, 0);
      accE[nt] = __builtin_amdgcn_mfma_f32_16x16x32_bf16(afe, bfv, accE[nt], 0, 0, 0);
    }
  }
  float sm[4] = {0, 0, 0, 0}, ssm[4] = {0, 0, 0, 0};
  float se[4] = {0, 0, 0, 0}, sse[4] = {0, 0, 0, 0};
#pragma unroll
  for (int r = 0; r < 4; ++r)
#pragma unroll
    for (int nt = 0; nt < 8; ++nt) {
      float vm = accM[nt][r] + bcol[nt];
      float ve = accE[nt][r] + bcol[nt];
      sm[r] += vm; ssm[r] += vm * vm;
      se[r] += ve; sse[r] += ve * ve;
    }
#pragma unroll
  for (int r = 0; r < 4; ++r) {
#pragma unroll
    for (int m = 1; m <= 8; m <<= 1) {
      sm[r] += __shfl_xor(sm[r], m, 64);
      ssm[r] += __shfl_xor(ssm[r], m, 64);
      se[r] += __shfl_xor(se[r], m, 64);
      sse[r] += __shfl_xor(sse[r], m, 64);
    }
  }

  if (!CSR) {
#pragma unroll
    for (int r = 0; r < 4; ++r) {
      int row = m0 + rowb + r;
      if (row >= E) continue;
      int rr = sR[rowb + r];
      float mean = sm[r] * (1.f / 128.f);
      float var = fmaxf(ssm[r] * (1.f / 128.f) - mean * mean, 0.f);
      float rstd = rsqrtf(var + 1e-5f);
#pragma unroll
      for (int nt = 0; nt < 8; ++nt) {
        float v = (accM[nt][r] + bcol[nt] - mean) * rstd * gcol[nt] + becol[nt];
        atomicAdd(&aggr[(size_t)rr * 128 + nt * 16 + l16], v);
      }
    }
  }

  __syncthreads();  // all LDS reads done; safe to overwrite
#pragma unroll
  for (int r = 0; r < 4; ++r) {
    float meanE = se[r] * (1.f / 128.f);
    float varE = fmaxf(sse[r] * (1.f / 128.f) - meanE * meanE, 0.f);
    float rstdE = rsqrtf(varE + 1e-5f);
    float meanM = sm[r] * (1.f / 128.f);
    float varM = fmaxf(ssm[r] * (1.f / 128.f) - meanM * meanM, 0.f);
    float rstdM = rsqrtf(varM + 1e-5f);
#pragma unroll
    for (int nt = 0; nt < 8; ++nt) {
      float ve = (accE[nt][r] + bcol[nt] - meanE) * rstdE * gcol[nt] + becol[nt];
      sHe[rowb + r][nt * 16 + l16] = fb(ve);
      if (CSR) {
        float vm = (accM[nt][r] + bcol[nt] - meanM) * rstdM * gcol[nt] + becol[nt];
        sHm[rowb + r][nt * 16 + l16] = fb(vm);
      }
    }
  }
  __syncthreads();

  // epilogue: eh residual+store; CSR: segmented aggregation of Ym rows
#pragma unroll
  for (int it = 0; it < 4; ++it) {
    int row = prow[it], ch = pch[it];
    int grow = m0 + row;
    if (grow >= E) continue;
    u16 y8[8], e8[8];
    *(uint4*)y8 = *(uint4*)(&sHe[row][ch]);
    *(uint4*)e8 = *(const uint4*)(eh + (size_t)grow * 128 + ch);
#pragma unroll
    for (int j = 0; j < 8; ++j) y8[j] = fb(bl(y8[j]) + bl(e8[j]));
    *(uint4*)(eh + (size_t)grow * 128 + ch) = *(uint4*)y8;

    if (CSR) {
      int rr = sR[row];
      bool first = (row == 0) || (sR[row - 1] != rr);
      if (!first) continue;
      int gs = startp[rr], ge2 = startp[rr + 1];
      int le = ge2 - m0;
      if (le > 64) le = 64;
      float acc[8] = {0, 0, 0, 0, 0, 0, 0, 0};
      for (int i = row; i < le; ++i) {
        u16 m8[8];
        *(uint4*)m8 = *(uint4*)(&sHm[i][ch]);
#pragma unroll
        for (int j = 0; j < 8; ++j) acc[j] += bl(m8[j]);
      }
      if (gs >= m0 && ge2 <= m0 + 64) {
        *(float4*)(aggr + (size_t)rr * 128 + ch) = make_float4(acc[0], acc[1], acc[2], acc[3]);
        *(float4*)(aggr + (size_t)rr * 128 + ch + 4) =
            make_float4(acc[4], acc[5], acc[6], acc[7]);
      } else {
#pragma unroll
        for (int j = 0; j < 8; ++j) atomicAdd(&aggr[(size_t)rr * 128 + ch + j], acc[j]);
      }
    }
  }
}

// decoder: wave per node, 128->64 swish -> 64->5, times dt
__global__ void decoder_kernel(const u16* __restrict__ xh, const float* __restrict__ w1,
                               const float* __restrict__ b1, const float* __restrict__ w2,
                               const float* __restrict__ b2, float* __restrict__ out,
                               int n_nodes) {
  __shared__ float sx[4][128];
  int tid = threadIdx.x;
  int lw = tid >> 6, lane = tid & 63;
  int n0 = blockIdx.x * 4;
  for (int i = tid; i < 512; i += 256) {
    int nn = i >> 7, c = i & 127;
    int n = n0 + nn;
    sx[nn][c] = (n < n_nodes) ? bl(xh[(size_t)n * 128 + c]) : 0.f;
  }
  __syncthreads();
  int n = n0 + lw;
  float h = b1[lane];
#pragma unroll 16
  for (int k = 0; k < 128; ++k) h += sx[lw][k] * w1[k * 64 + lane];
  float hs = h * (1.f / (1.f + __expf(-h)));
  float d[5];
#pragma unroll
  for (int t = 0; t < 5; ++t) {
    float p = hs * w2[lane * 5 + t];
#pragma unroll
    for (int m = 1; m <= 32; m <<= 1) p += __shfl_xor(p, m, 64);
    d[t] = p;
  }
  if (lane == 0 && n < n_nodes) {
#pragma unroll
    for (int t = 0; t < 5; ++t)
      out[(size_t)n * 5 + t] = (float)(t + 1) * (d[t] + b2[t]);
  }
}

extern "C" void kernel_launch(void* const* d_in, const int* in_sizes, int n_in, void* d_out,
                              int out_size, void* d_ws, size_t ws_size, hipStream_t stream) {
  auto F = [&](int i) { return (const float*)d_in[i]; };
  const int* edge_index = (const int*)d_in[6];
  const int N_ = in_sizes[0];
  const int E_ = in_sizes[6] / 2;

  char* wsb = (char*)d_ws;
  size_t off = 0;
  auto alloc = [&](size_t bytes) -> char* {
    char* p = wsb + off;
    off += (bytes + 255) & ~(size_t)255;
    return p;
  };
  u16* xh = (u16*)alloc((size_t)N_ * 128 * 2);
  u16* xhA = (u16*)alloc((size_t)N_ * 128 * 2);
  u16* xhB = (u16*)alloc((size_t)N_ * 128 * 2);
  u16* h1n = (u16*)alloc((size_t)N_ * 128 * 2);
  u16* ehP = (u16*)alloc((size_t)E_ * 128 * 2);
  float* aggr = (float*)alloc((size_t)N_ * 128 * 4);
  float* nfeat = (float*)xhA;  // alias (dead before xhA live)
  float* efeat = (float*)xhB;  // alias
  u16* wne2T = (u16*)alloc(16384 * 2);
  u16* wee2T = (u16*)alloc(16384 * 2);
  u16* wpe1T = (u16*)alloc((size_t)9 * 16384 * 2);
  u16* wpe2T = (u16*)alloc((size_t)3 * 16384 * 2);
  u16* wpn1T = (u16*)alloc((size_t)6 * 16384 * 2);
  u16* wpn2T = (u16*)alloc((size_t)3 * 16384 * 2);

  const size_t base_off = off;
  int* startp = (int*)alloc((size_t)(N_ + 1) * 4);
  int* cntp = (int*)alloc((size_t)N_ * 4);
  int* partp = (int*)alloc((size_t)N_ * 4);
  int* bsump = (int*)alloc(((size_t)(N_ + 255) / 256) * 4 + 256);
  int* sortedS = (int*)alloc((size_t)E_ * 4);
  int* sortedR = (int*)alloc((size_t)E_ * 4);
  bool useCSR = (off <= ws_size);
  if (!useCSR) {
    off = base_off;
    if (off > ws_size) {
      sentinel_kernel<<<(out_size + 255) / 256, 256, 0, stream>>>((float*)d_out, out_size);
      return;
    }
  }

  TArgs ta;
  int ts = 0;
  ta.s[ts++] = {F(13), wne2T};
  ta.s[ts++] = {F(19), wee2T};
  for (int i = 0; i < 3; ++i)
    for (int b = 0; b < 3; ++b)
      ta.s[ts++] = {F(23) + (size_t)(i * 3 + b) * 16384, wpe1T + (size_t)(i * 3 + b) * 16384};
  for (int i = 0; i < 3; ++i) ta.s[ts++] = {F(25) + (size_t)i * 16384, wpe2T + (size_t)i * 16384};
  for (int i = 0; i < 3; ++i)
    for (int b = 0; b < 2; ++b)
      ta.s[ts++] = {F(29) + (size_t)(i * 2 + b) * 16384, wpn1T + (size_t)(i * 2 + b) * 16384};
  for (int i = 0; i < 3; ++i) ta.s[ts++] = {F(31) + (size_t)i * 16384, wpn2T + (size_t)i * 16384};

  const int tilesN = (N_ + 63) / 64;
  const int tilesE = (E_ + 63) / 64;
  const int nb = (N_ + 255) / 256;
  dim3 blk(256);

  transpose_w<<<23, blk, 0, stream>>>(ta);

  const int* sArr = edge_index;
  const int* rArr = edge_index + E_;
  if (useCSR) {
    zero_i32<<<(N_ + 255) / 256, blk, 0, stream>>>(cntp, N_);
    deg_count<<<(E_ + 255) / 256, blk, 0, stream>>>(edge_index, cntp, E_);
    scan1<<<nb, blk, 0, stream>>>(cntp, partp, bsump, N_);
    scan2<<<1, blk, 0, stream>>>(bsump, nb);
    scan3<<<nb, blk, 0, stream>>>(partp, bsump, startp, N_);
    zero_i32<<<(N_ + 255) / 256, blk, 0, stream>>>(cntp, N_);
    fill_slot<<<(E_ + 255) / 256, blk, 0, stream>>>(edge_index, cntp, startp, sortedS, sortedR,
                                                    E_);
    sArr = sortedS;
    rArr = sortedR;
  }

  // ---- encode ----
  node_feat_kernel<<<(N_ + 255) / 256, blk, 0, stream>>>(F(0), F(1), F(2), F(3), F(4), F(7),
                                                         F(8), nfeat, N_);
  enc1_kernel<9><<<(N_ * 128 + 255) / 256, blk, 0, stream>>>(nfeat, F(11), F(12), h1n, N_);
  gemm64<GM_LN, false, false><<<tilesN, blk, 0, stream>>>(h1n, wne2T, nullptr, nullptr, F(14),
                                                          F(15), F(16), nullptr, xh, N_);
  edge_feat_kernel<<<(E_ + 255) / 256, blk, 0, stream>>>(sArr, rArr, F(5), F(0), F(9), F(10),
                                                         efeat, E_);
  enc1_kernel<4><<<(E_ * 128 + 255) / 256, blk, 0, stream>>>(efeat, F(17), F(18), ehP, E_);
  gemm64<GM_LN, false, false><<<tilesE, blk, 0, stream>>>(ehP, wee2T, nullptr, nullptr, F(20),
                                                          F(21), F(22), nullptr, ehP, E_);

  // ---- process steps ----
  for (int i = 0; i < 3; ++i) {
    const u16* wtA = wpe1T + (size_t)(i * 3 + 0) * 16384;
    const u16* wtB = wpe1T + (size_t)(i * 3 + 1) * 16384;
    const u16* wtC = wpe1T + (size_t)(i * 3 + 2) * 16384;
    const float* pb1 = F(24) + i * 128;
    const u16* wt2 = wpe2T + (size_t)i * 16384;
    const float* pb2 = F(26) + i * 128;
    const float* pg = F(27) + i * 128;
    const float* pbe = F(28) + i * 128;
    const u16* wtnA = wpn1T + (size_t)(i * 2 + 0) * 16384;
    const u16* wtnB = wpn1T + (size_t)(i * 2 + 1) * 16384;
    const float* nb1 = F(30) + i * 128;
    const u16* wtn2 = wpn2T + (size_t)i * 16384;
    const float* nb2 = F(32) + i * 128;
    const float* ng = F(33) + i * 128;
    const float* nbe = F(34) + i * 128;

    gemm64_2w<<<tilesN, blk, 0, stream>>>(xh, wtA, wtB, xhA, xhB, aggr, N_);
    if (useCSR) {
      edge_fused<true><<<tilesE, blk, 0, stream>>>(ehP, xhA, xhB, wtC, pb1, wt2, pb2, pg, pbe,
                                                   sArr, rArr, startp, aggr, E_);
    } else {
      edge_fused<false><<<tilesE, blk, 0, stream>>>(ehP, xhA, xhB, wtC, pb1, wt2, pb2, pg, pbe,
                                                    sArr, rArr, nullptr, aggr, E_);
    }
    node_fused<<<tilesN, blk, 0, stream>>>(xh, aggr, wtnA, wtnB, nb1, wtn2, nb2, ng, nbe, N_);
  }

  // ---- decode ----
  decoder_kernel<<<(N_ + 3) / 4, blk, 0, stream>>>(xh, F(35), F(36), F(37), F(38),
                                                   (float*)d_out, N_);
}

// Round 17
// 1298.753 us; speedup vs baseline: 1.1715x; 1.0111x over previous
//
#include <hip/hip_runtime.h>
#include <stdint.h>

typedef unsigned short u16;
typedef __attribute__((ext_vector_type(8))) short bf16x8_t;
typedef __attribute__((ext_vector_type(4))) float f32x4_t;

__device__ __forceinline__ float bl(u16 x) {
  union { unsigned u; float f; } c; c.u = ((unsigned)x) << 16; return c.f;
}
__device__ __forceinline__ u16 fb(float x) {
  union { float f; unsigned u; } c; c.f = x;
  unsigned r = c.u + 0x7fffu + ((c.u >> 16) & 1u);
  return (u16)(r >> 16);
}

__global__ void sentinel_kernel(float* out, int n) {
  int i = blockIdx.x * 256 + threadIdx.x;
  if (i < n) out[i] = 12345.f;
}

// ---------------- weight transpose: wT[n][k] = fb(W[k][n]) ----------------
struct TSeg { const float* src; u16* dst; };
struct TArgs { TSeg s[23]; };
__global__ void transpose_w(TArgs a) {
  const float* src = a.s[blockIdx.x].src;
  u16* dst = a.s[blockIdx.x].dst;
  for (int e = threadIdx.x; e < 16384; e += 256) {
    int n = e >> 7, k = e & 127;
    dst[e] = fb(src[k * 128 + n]);
  }
}

// ---------------- CSR build + receiver-sort ----------------
__global__ void zero_i32(int* p, int n) {
  int i = blockIdx.x * 256 + threadIdx.x;
  if (i < n) p[i] = 0;
}
__global__ void deg_count(const int* __restrict__ ei, int* __restrict__ cnt, int E) {
  int e = blockIdx.x * 256 + threadIdx.x;
  if (e < E) atomicAdd(&cnt[ei[E + e]], 1);
}
__global__ void scan1(const int* __restrict__ cnt, int* __restrict__ part,
                      int* __restrict__ bsum, int N) {
  __shared__ int s[256];
  int i = blockIdx.x * 256 + threadIdx.x;
  s[threadIdx.x] = (i < N) ? cnt[i] : 0;
  __syncthreads();
#pragma unroll
  for (int o = 1; o < 256; o <<= 1) {
    int t = (threadIdx.x >= o) ? s[threadIdx.x - o] : 0;
    __syncthreads();
    s[threadIdx.x] += t;
    __syncthreads();
  }
  if (i < N) part[i] = s[threadIdx.x];
  if (threadIdx.x == 255) bsum[blockIdx.x] = s[255];
}
__global__ void scan2(int* bsum, int nb) {
  if (threadIdx.x == 0 && blockIdx.x == 0) {
    int acc = 0;
    for (int i = 0; i < nb; ++i) { int t = bsum[i]; bsum[i] = acc; acc += t; }
  }
}
__global__ void scan3(const int* __restrict__ part, const int* __restrict__ bsum,
                      int* __restrict__ start, int N) {
  int i = blockIdx.x * 256 + threadIdx.x;
  if (i < N) start[i + 1] = part[i] + bsum[i >> 8];
  if (i == 0) start[0] = 0;
}
__global__ void fill_slot(const int* __restrict__ ei, int* __restrict__ cnt2,
                          const int* __restrict__ start, int* __restrict__ sortedS,
                          int* __restrict__ sortedR, int E) {
  int e = blockIdx.x * 256 + threadIdx.x;
  if (e >= E) return;
  int s = ei[e], r = ei[E + e];
  int p = atomicAdd(&cnt2[r], 1);
  int slot = start[r] + p;
  sortedS[slot] = s;
  sortedR[slot] = r;
}

// ---------------- feature kernels ----------------
__global__ void node_feat_kernel(const float* __restrict__ t, const float* __restrict__ tp,
                                 const float* __restrict__ q, const float* __restrict__ qp,
                                 const float* __restrict__ qn, const float* __restrict__ nm,
                                 const float* __restrict__ ns, float* __restrict__ nfeat,
                                 int n_nodes) {
  int n = blockIdx.x * 256 + threadIdx.x;
  if (n >= n_nodes) return;
  float u = t[n];
  float x[9];
  x[0] = u; x[1] = u - tp[n];
  float hq = q[n];
  x[2] = hq; x[3] = hq - qp[n];
#pragma unroll
  for (int j = 0; j < 5; ++j) x[4 + j] = qn[n * 5 + j];
#pragma unroll
  for (int k = 0; k < 9; ++k) nfeat[n * 9 + k] = (x[k] - nm[k]) / ns[k];
}

__global__ void edge_feat_kernel(const int* __restrict__ sArr, const int* __restrict__ rArr,
                                 const float* __restrict__ mp, const float* __restrict__ u,
                                 const float* __restrict__ em, const float* __restrict__ es,
                                 float* __restrict__ efeat, int n_edges) {
  int e = blockIdx.x * 256 + threadIdx.x;
  if (e >= n_edges) return;
  int s = sArr[e], r = rArr[e];
  float rx = mp[s * 2] - mp[r * 2];
  float ry = mp[s * 2 + 1] - mp[r * 2 + 1];
  float d = sqrtf(rx * rx + ry * ry);
  float rt = u[s] - u[r];
  float x[4] = {rx, ry, d, rt};
#pragma unroll
  for (int k = 0; k < 4; ++k) efeat[e * 4 + k] = (x[k] - em[k]) / es[k];
}

template <int K>
__global__ void enc1_kernel(const float* __restrict__ feat, const float* __restrict__ w1,
                            const float* __restrict__ b1, u16* __restrict__ out, int M) {
  int gid = blockIdx.x * 256 + threadIdx.x;
  int n = gid >> 7, h = gid & 127;
  if (n >= M) return;
  float acc = b1[h];
#pragma unroll
  for (int k = 0; k < K; ++k) acc += feat[n * K + k] * w1[k * 128 + h];
  out[n * 128 + h] = fb(acc > 0.f ? acc : 0.f);
}

// ---------------- LDS-free-GEMM + LDS-staged vector-store epilogue ----------------
#define GM_NONE 0
#define GM_RELU 1
#define GM_LN 2

template <int MODE, bool DUAL, bool A0F32>
__global__ __launch_bounds__(256, 2) void gemm64(
    const void* __restrict__ A0v, const u16* __restrict__ WT0, const u16* __restrict__ A1,
    const u16* __restrict__ WT1, const float* __restrict__ bias, const float* __restrict__ gg,
    const float* __restrict__ bb, const u16* __restrict__ resid, u16* __restrict__ out, int M) {
  __shared__ u16 sO[64][136];
  const int tid = threadIdx.x;
  const int wave = tid >> 6, lane = tid & 63;
  const int q = lane >> 4, l16 = lane & 15;
  const int m0 = blockIdx.x * 64;
  int arow = m0 + wave * 16 + l16;
  if (arow >= M) arow = M - 1;

  f32x4_t acc[8];
#pragma unroll
  for (int b = 0; b < 8; ++b) acc[b] = (f32x4_t){0.f, 0.f, 0.f, 0.f};

  const int NKT = DUAL ? 2 : 1;
#pragma unroll 1
  for (int kt = 0; kt < NKT; ++kt) {
    const u16* WT = kt ? WT1 : WT0;
#pragma unroll
    for (int kk = 0; kk < 4; ++kk) {
      bf16x8_t af;
      if (A0F32 && kt == 0) {
        const float* ap = (const float*)A0v + (size_t)arow * 128 + kk * 32 + q * 8;
        union { u16 u[8]; bf16x8_t v; } cv;
#pragma unroll
        for (int j = 0; j < 8; ++j) cv.u[j] = fb(ap[j]);
        af = cv.v;
      } else {
        const u16* ap = (kt ? A1 : (const u16*)A0v) + (size_t)arow * 128 + kk * 32 + q * 8;
        af = *(const bf16x8_t*)ap;
      }
      const u16* wp = WT + kk * 32 + q * 8;
#pragma unroll
      for (int nt = 0; nt < 8; ++nt) {
        bf16x8_t bfv = *(const bf16x8_t*)(wp + (size_t)(nt * 16 + l16) * 128);
        acc[nt] = __builtin_amdgcn_mfma_f32_16x16x32_bf16(af, bfv, acc[nt], 0, 0, 0);
      }
    }
  }

  const int rowb = wave * 16 + q * 4;
  if (MODE == GM_NONE) {
#pragma unroll
    for (int r = 0; r < 4; ++r)
#pragma unroll
      for (int nt = 0; nt < 8; ++nt) sO[rowb + r][nt * 16 + l16] = fb(acc[nt][r]);
  } else if (MODE == GM_RELU) {
    float bcol[8];
#pragma unroll
    for (int nt = 0; nt < 8; ++nt) bcol[nt] = bias[nt * 16 + l16];
#pragma unroll
    for (int r = 0; r < 4; ++r)
#pragma unroll
      for (int nt = 0; nt < 8; ++nt) {
        float v = acc[nt][r] + bcol[nt];
        sO[rowb + r][nt * 16 + l16] = fb(v > 0.f ? v : 0.f);
      }
  } else {
    float bcol[8], gcol[8], becol[8];
#pragma unroll
    for (int nt = 0; nt < 8; ++nt) {
      bcol[nt] = bias[nt * 16 + l16];
      gcol[nt] = gg[nt * 16 + l16];
      becol[nt] = bb[nt * 16 + l16];
    }
    float s[4] = {0, 0, 0, 0}, ss[4] = {0, 0, 0, 0};
#pragma unroll
    for (int r = 0; r < 4; ++r)
#pragma unroll
      for (int nt = 0; nt < 8; ++nt) {
        float v = acc[nt][r] + bcol[nt];
        s[r] += v;
        ss[r] += v * v;
      }
#pragma unroll
    for (int r = 0; r < 4; ++r) {
#pragma unroll
      for (int m = 1; m <= 8; m <<= 1) {
        s[r] += __shfl_xor(s[r], m, 64);
        ss[r] += __shfl_xor(ss[r], m, 64);
      }
    }
#pragma unroll
    for (int r = 0; r < 4; ++r) {
      float mean = s[r] * (1.f / 128.f);
      float var = fmaxf(ss[r] * (1.f / 128.f) - mean * mean, 0.f);
      float rstd = rsqrtf(var + 1e-5f);
#pragma unroll
      for (int nt = 0; nt < 8; ++nt) {
        float v = (acc[nt][r] + bcol[nt] - mean) * rstd * gcol[nt] + becol[nt];
        sO[rowb + r][nt * 16 + l16] = fb(v);
      }
    }
  }
  __syncthreads();
#pragma unroll
  for (int it = 0; it < 4; ++it) {
    int lin = it * 256 + tid;
    int row = lin >> 4, ch = (lin & 15) * 8;
    int grow = m0 + row;
    if (grow >= M) continue;
    u16 o8[8];
    *(uint4*)o8 = *(uint4*)(&sO[row][ch]);
    if (MODE == GM_LN && resid) {
      u16 r8[8];
      *(uint4*)r8 = *(const uint4*)(resid + (size_t)grow * 128 + ch);
#pragma unroll
      for (int j = 0; j < 8; ++j) o8[j] = fb(bl(o8[j]) + bl(r8[j]));
    }
    *(uint4*)(out + (size_t)grow * 128 + ch) = *(uint4*)o8;
  }
}

// dual-output GEMM: out0 = A@W0, out1 = A@W1 (A read once); also zeroes aggr rows
__global__ __launch_bounds__(256, 2) void gemm64_2w(
    const u16* __restrict__ A, const u16* __restrict__ WT0, const u16* __restrict__ WT1,
    u16* __restrict__ out0, u16* __restrict__ out1, float* __restrict__ aggr, int M) {
  __shared__ u16 sO0[64][136];
  __shared__ u16 sO1[64][136];
  const int tid = threadIdx.x;
  const int wave = tid >> 6, lane = tid & 63;
  const int q = lane >> 4, l16 = lane & 15;
  const int m0 = blockIdx.x * 64;
  int arow = m0 + wave * 16 + l16;
  if (arow >= M) arow = M - 1;

  {
    float4 z = make_float4(0.f, 0.f, 0.f, 0.f);
#pragma unroll
    for (int it = 0; it < 8; ++it) {
      int lin = it * 256 + tid;
      int row = lin >> 5, c4 = (lin & 31) * 4;
      int grow = m0 + row;
      if (grow < M) *(float4*)(aggr + (size_t)grow * 128 + c4) = z;
    }
  }

  f32x4_t a0[8], a1[8];
#pragma unroll
  for (int b = 0; b < 8; ++b) {
    a0[b] = (f32x4_t){0.f, 0.f, 0.f, 0.f};
    a1[b] = (f32x4_t){0.f, 0.f, 0.f, 0.f};
  }
#pragma unroll 2
  for (int kk = 0; kk < 4; ++kk) {
    bf16x8_t af = *(const bf16x8_t*)(A + (size_t)arow * 128 + kk * 32 + q * 8);
#pragma unroll
    for (int nt = 0; nt < 8; ++nt) {
      bf16x8_t b0 = *(const bf16x8_t*)(WT0 + (size_t)(nt * 16 + l16) * 128 + kk * 32 + q * 8);
      bf16x8_t b1v = *(const bf16x8_t*)(WT1 + (size_t)(nt * 16 + l16) * 128 + kk * 32 + q * 8);
      a0[nt] = __builtin_amdgcn_mfma_f32_16x16x32_bf16(af, b0, a0[nt], 0, 0, 0);
      a1[nt] = __builtin_amdgcn_mfma_f32_16x16x32_bf16(af, b1v, a1[nt], 0, 0, 0);
    }
  }
  const int rowb = wave * 16 + q * 4;
#pragma unroll
  for (int r = 0; r < 4; ++r)
#pragma unroll
    for (int nt = 0; nt < 8; ++nt) {
      sO0[rowb + r][nt * 16 + l16] = fb(a0[nt][r]);
      sO1[rowb + r][nt * 16 + l16] = fb(a1[nt][r]);
    }
  __syncthreads();
#pragma unroll
  for (int it = 0; it < 4; ++it) {
    int lin = it * 256 + tid;
    int row = lin >> 4, ch = (lin & 15) * 8;
    int grow = m0 + row;
    if (grow >= M) continue;
    *(uint4*)(out0 + (size_t)grow * 128 + ch) = *(uint4*)(&sO0[row][ch]);
    *(uint4*)(out1 + (size_t)grow * 128 + ch) = *(uint4*)(&sO1[row][ch]);
  }
}

// ---------------- fused node-update (+ next-step dual GEMM) ----------------
// xh = LN(relu(aggr@WA + xh@WB + b1)@W2 + b2) + xh; if wtA2: emit xhA/xhB = xh_new@{WA2,WB2}
// and zero this block's aggr rows for the next step.
__global__ __launch_bounds__(256, 2) void node_fused_2w(
    u16* __restrict__ xh, float* __restrict__ aggr, const u16* __restrict__ wtA,
    const u16* __restrict__ wtB, const float* __restrict__ b1, const u16* __restrict__ wt2,
    const float* __restrict__ b2, const float* __restrict__ gg, const float* __restrict__ bb,
    const u16* __restrict__ wtA2, const u16* __restrict__ wtB2, u16* __restrict__ xhA,
    u16* __restrict__ xhB, int M) {
  __shared__ u16 sH[64][136];
  __shared__ u16 sO1[64][136];
  const int tid = threadIdx.x;
  const int wave = tid >> 6, lane = tid & 63;
  const int q = lane >> 4, l16 = lane & 15;
  const int m0 = blockIdx.x * 64;
  const int rowb = wave * 16 + q * 4;
  const int arow = m0 + wave * 16 + l16;
  const int arc = arow < M ? arow : M - 1;

  bf16x8_t xf[4], af_[4];
#pragma unroll
  for (int kk = 0; kk < 4; ++kk) {
    xf[kk] = *(const bf16x8_t*)(xh + (size_t)arc * 128 + kk * 32 + q * 8);
    const float* ap = aggr + (size_t)arc * 128 + kk * 32 + q * 8;
    union { u16 u[8]; bf16x8_t v; } cv;
#pragma unroll
    for (int j = 0; j < 8; ++j) cv.u[j] = fb(ap[j]);
    af_[kk] = cv.v;
  }

  // GEMM1: relu(aggr@WA + xh@WB + b1) -> sH
  f32x4_t acc[8];
#pragma unroll
  for (int b = 0; b < 8; ++b) acc[b] = (f32x4_t){0.f, 0.f, 0.f, 0.f};
#pragma unroll
  for (int kk = 0; kk < 4; ++kk) {
#pragma unroll
    for (int nt = 0; nt < 8; ++nt) {
      bf16x8_t bA = *(const bf16x8_t*)(wtA + (size_t)(nt * 16 + l16) * 128 + kk * 32 + q * 8);
      bf16x8_t bB = *(const bf16x8_t*)(wtB + (size_t)(nt * 16 + l16) * 128 + kk * 32 + q * 8);
      acc[nt] = __builtin_amdgcn_mfma_f32_16x16x32_bf16(af_[kk], bA, acc[nt], 0, 0, 0);
      acc[nt] = __builtin_amdgcn_mfma_f32_16x16x32_bf16(xf[kk], bB, acc[nt], 0, 0, 0);
    }
  }
  float bcol1[8];
#pragma unroll
  for (int nt = 0; nt < 8; ++nt) bcol1[nt] = b1[nt * 16 + l16];
#pragma unroll
  for (int r = 0; r < 4; ++r)
#pragma unroll
    for (int nt = 0; nt < 8; ++nt) {
      float v = acc[nt][r] + bcol1[nt];
      sH[rowb + r][nt * 16 + l16] = fb(v > 0.f ? v : 0.f);
    }
  __syncthreads();

  // GEMM2 + LN
  f32x4_t acc2[8];
#pragma unroll
  for (int b = 0; b < 8; ++b) acc2[b] = (f32x4_t){0.f, 0.f, 0.f, 0.f};
#pragma unroll
  for (int kk = 0; kk < 4; ++kk) {
    bf16x8_t afm = *(const bf16x8_t*)(&sH[wave * 16 + l16][kk * 32 + q * 8]);
#pragma unroll
    for (int nt = 0; nt < 8; ++nt) {
      bf16x8_t bfv = *(const bf16x8_t*)(wt2 + (size_t)(nt * 16 + l16) * 128 + kk * 32 + q * 8);
      acc2[nt] = __builtin_amdgcn_mfma_f32_16x16x32_bf16(afm, bfv, acc2[nt], 0, 0, 0);
    }
  }
  float bcol[8], gcol[8], becol[8];
#pragma unroll
  for (int nt = 0; nt < 8; ++nt) {
    bcol[nt] = b2[nt * 16 + l16];
    gcol[nt] = gg[nt * 16 + l16];
    becol[nt] = bb[nt * 16 + l16];
  }
  float s[4] = {0, 0, 0, 0}, ss[4] = {0, 0, 0, 0};
#pragma unroll
  for (int r = 0; r < 4; ++r)
#pragma unroll
    for (int nt = 0; nt < 8; ++nt) {
      float v = acc2[nt][r] + bcol[nt];
      s[r] += v;
      ss[r] += v * v;
    }
#pragma unroll
  for (int r = 0; r < 4; ++r) {
#pragma unroll
    for (int m = 1; m <= 8; m <<= 1) {
      s[r] += __shfl_xor(s[r], m, 64);
      ss[r] += __shfl_xor(ss[r], m, 64);
    }
  }
  __syncthreads();  // GEMM2 reads done
#pragma unroll
  for (int r = 0; r < 4; ++r) {
    float mean = s[r] * (1.f / 128.f);
    float var = fmaxf(ss[r] * (1.f / 128.f) - mean * mean, 0.f);
    float rstd = rsqrtf(var + 1e-5f);
#pragma unroll
    for (int nt = 0; nt < 8; ++nt) {
      float v = (acc2[nt][r] + bcol[nt] - mean) * rstd * gcol[nt] + becol[nt];
      sH[rowb + r][nt * 16 + l16] = fb(v);
    }
  }
  __syncthreads();

  // epilogue: new xh fragments (A-mapping, in-register residual)
  bf16x8_t nf[4];
#pragma unroll
  for (int kk = 0; kk < 4; ++kk) {
    u16 y8[8];
    *(uint4*)y8 = *(uint4*)(&sH[wave * 16 + l16][kk * 32 + q * 8]);
#pragma unroll
    for (int j = 0; j < 8; ++j) y8[j] = fb(bl(y8[j]) + bl((u16)xf[kk][j]));
    nf[kk] = *(bf16x8_t*)y8;
    if (arow < M)
      *(uint4*)(xh + (size_t)arow * 128 + kk * 32 + q * 8) = *(uint4*)y8;
  }

  if (wtA2 == nullptr) return;

  // zero this block's aggr rows for next step (genuine rows only; per-lane exclusive chunks)
  if (arow < M) {
    float4 z = make_float4(0.f, 0.f, 0.f, 0.f);
#pragma unroll
    for (int kk = 0; kk < 4; ++kk) {
      *(float4*)(aggr + (size_t)arow * 128 + kk * 32 + q * 8) = z;
      *(float4*)(aggr + (size_t)arow * 128 + kk * 32 + q * 8 + 4) = z;
    }
  }

  // next-step dual GEMM from in-register new xh fragments
  f32x4_t a0[8], a1[8];
#pragma unroll
  for (int b = 0; b < 8; ++b) {
    a0[b] = (f32x4_t){0.f, 0.f, 0.f, 0.f};
    a1[b] = (f32x4_t){0.f, 0.f, 0.f, 0.f};
  }
#pragma unroll
  for (int kk = 0; kk < 4; ++kk) {
#pragma unroll
    for (int nt = 0; nt < 8; ++nt) {
      bf16x8_t b0 = *(const bf16x8_t*)(wtA2 + (size_t)(nt * 16 + l16) * 128 + kk * 32 + q * 8);
      bf16x8_t b1v = *(const bf16x8_t*)(wtB2 + (size_t)(nt * 16 + l16) * 128 + kk * 32 + q * 8);
      a0[nt] = __builtin_amdgcn_mfma_f32_16x16x32_bf16(nf[kk], b0, a0[nt], 0, 0, 0);
      a1[nt] = __builtin_amdgcn_mfma_f32_16x16x32_bf16(nf[kk], b1v, a1[nt], 0, 0, 0);
    }
  }
  __syncthreads();  // all epilogue sH reads complete before overwrite
#pragma unroll
  for (int r = 0; r < 4; ++r)
#pragma unroll
    for (int nt = 0; nt < 8; ++nt) {
      sH[rowb + r][nt * 16 + l16] = fb(a0[nt][r]);
      sO1[rowb + r][nt * 16 + l16] = fb(a1[nt][r]);
    }
  __syncthreads();
#pragma unroll
  for (int it = 0; it < 4; ++it) {
    int lin = it * 256 + tid;
    int row = lin >> 4, ch = (lin & 15) * 8;
    int grow = m0 + row;
    if (grow >= M) continue;
    *(uint4*)(xhA + (size_t)grow * 128 + ch) = *(uint4*)(&sH[row][ch]);
    *(uint4*)(xhB + (size_t)grow * 128 + ch) = *(uint4*)(&sO1[row][ch]);
  }
}

// ---------------- fused edge kernel (round-12 champion) ----------------
template <bool CSR>
__global__ __launch_bounds__(256, 2) void edge_fused(
    u16* __restrict__ eh, const u16* __restrict__ xhA, const u16* __restrict__ xhB,
    const u16* __restrict__ wtC, const float* __restrict__ b1, const u16* __restrict__ wt2,
    const float* __restrict__ b2, const float* __restrict__ gg, const float* __restrict__ bb,
    const int* __restrict__ sArr, const int* __restrict__ rArr,
    const int* __restrict__ startp, float* __restrict__ aggr, int E) {
  __shared__ u16 sHm[64][136];
  __shared__ u16 sHe[64][136];
  __shared__ int sR[64];
  const int tid = threadIdx.x;
  const int wave = tid >> 6, lane = tid & 63;
  const int q = lane >> 4, l16 = lane & 15;
  const int m0 = blockIdx.x * 64;
  const int rowb = wave * 16 + q * 4;
  int arow = m0 + wave * 16 + l16;
  int arc = arow < E ? arow : E - 1;

  if (tid < 64) {
    int e = m0 + tid;
    sR[tid] = (e < E) ? rArr[e] : -1;
  }

  int prow[4], pch[4], pr_[4];
  uint4 pAs[4], pBs[4];
#pragma unroll
  for (int it = 0; it < 4; ++it) {
    int lin = it * 256 + tid;
    prow[it] = lin >> 4;
    pch[it] = (lin & 15) * 8;
    int ge = m0 + prow[it];
    int gc = ge < E ? ge : E - 1;
    int ps = sArr[gc];
    pr_[it] = rArr[gc];
    pAs[it] = *(const uint4*)(xhA + (size_t)ps * 128 + pch[it]);
    pBs[it] = *(const uint4*)(xhB + (size_t)ps * 128 + pch[it]);
  }
  bf16x8_t ehf[4];
#pragma unroll
  for (int kk = 0; kk < 4; ++kk)
    ehf[kk] = *(const bf16x8_t*)(eh + (size_t)arc * 128 + kk * 32 + q * 8);

  f32x4_t accC[8];
#pragma unroll
  for (int b = 0; b < 8; ++b) accC[b] = (f32x4_t){0.f, 0.f, 0.f, 0.f};
#pragma unroll
  for (int kk = 0; kk < 4; ++kk) {
#pragma unroll
    for (int nt = 0; nt < 8; ++nt) {
      bf16x8_t bfv = *(const bf16x8_t*)(wtC + (size_t)(nt * 16 + l16) * 128 + kk * 32 + q * 8);
      accC[nt] = __builtin_amdgcn_mfma_f32_16x16x32_bf16(ehf[kk], bfv, accC[nt], 0, 0, 0);
    }
  }
#pragma unroll
  for (int r = 0; r < 4; ++r)
#pragma unroll
    for (int nt = 0; nt < 8; ++nt) sHm[rowb + r][nt * 16 + l16] = fb(accC[nt][r]);
  __syncthreads();

#pragma unroll
  for (int it = 0; it < 4; ++it) {
    int row = prow[it], ch = pch[it];
    bool ok = (m0 + row) < E;
    int r_ = pr_[it] >= 0 ? pr_[it] : 0;
    u16 t8[8], ar[8], as_[8], br[8], bs[8], hm[8], he[8];
    *(uint4*)t8 = *(uint4*)(&sHm[row][ch]);
    *(uint4*)ar = *(const uint4*)(xhA + (size_t)r_ * 128 + ch);
    *(uint4*)br = *(const uint4*)(xhB + (size_t)r_ * 128 + ch);
    *(uint4*)as_ = pAs[it];
    *(uint4*)bs = pBs[it];
#pragma unroll
    for (int j = 0; j < 8; ++j) {
      float t = bl(t8[j]) + b1[ch + j];
      float vm = t + bl(ar[j]) + bl(bs[j]);
      float ve = t + bl(as_[j]) + bl(br[j]);
      hm[j] = (ok && vm > 0.f) ? fb(vm) : 0;
      he[j] = (ok && ve > 0.f) ? fb(ve) : 0;
    }
    *(uint4*)(&sHm[row][ch]) = *(uint4*)hm;
    *(uint4*)(&sHe[row][ch]) = *(uint4*)he;
  }
  __syncthreads();

  float bcol[8], gcol[8], becol[8];
#pragma unroll
  for (int nt = 0; nt < 8; ++nt) {
    bcol[nt] = b2[nt * 16 + l16];
    gcol[nt] = gg[nt * 16 + l16];
    becol[nt] = bb[nt * 16 + l16];
  }

  f32x4_t accM[8], accE[8];
#pragma unroll
  for (int b = 0; b < 8; ++b) {
    accM[b] = (f32x4_t){0.f, 0.f, 0.f, 0.f};
    accE[b] = (f32x4_t){0.f, 0.f, 0.f, 0.f};
  }
#pragma unroll
  for (int kk = 0; kk < 4; ++kk) {
    bf16x8_t afm = *(const bf16x8_t*)(&sHm[wave * 16 + l16][kk * 32 + q * 8]);
    bf16x8_t afe = *(const bf16x8_t*)(&sHe[wave * 16 + l16][kk * 32 + q * 8]);
#pragma unroll
    for (int nt = 0; nt < 8; ++nt) {
      bf16x8_t bfv = *(const bf16x8_t*)(wt2 + (size_t)(nt * 16 + l16) * 128 + kk * 32 + q * 8);
      accM[nt] = __builtin_amdgcn_mfma_f32_16x16x32_bf16(afm, bfv, accM[nt], 0, 0, 0);
      accE[nt] = __builtin_amdgcn_mfma_f32_16x16x32_bf16(afe, bfv, accE[nt], 0, 0, 0);
    }
  }
  float sm[4] = {0, 0, 0, 0}, ssm[4] = {0, 0, 0, 0};
  float se[4] = {0, 0, 0, 0}, sse[4] = {0, 0, 0, 0};
#pragma unroll
  for (int r = 0; r < 4; ++r)
#pragma unroll
    for (int nt = 0; nt < 8; ++nt) {
      float vm = accM[nt][r] + bcol[nt];
      float ve = accE[nt][r] + bcol[nt];
      sm[r] += vm; ssm[r] += vm * vm;
      se[r] += ve; sse[r] += ve * ve;
    }
#pragma unroll
  for (int r = 0; r < 4; ++r) {
#pragma unroll
    for (int m = 1; m <= 8; m <<= 1) {
      sm[r] += __shfl_xor(sm[r], m, 64);
      ssm[r] += __shfl_xor(ssm[r], m, 64);
      se[r] += __shfl_xor(se[r], m, 64);
      sse[r] += __shfl_xor(sse[r], m, 64);
    }
  }

  if (!CSR) {
#pragma unroll
    for (int r = 0; r < 4; ++r) {
      int row = m0 + rowb + r;
      if (row >= E) continue;
      int rr = sR[rowb + r];
      float mean = sm[r] * (1.f / 128.f);
      float var = fmaxf(ssm[r] * (1.f / 128.f) - mean * mean, 0.f);
      float rstd = rsqrtf(var + 1e-5f);
#pragma unroll
      for (int nt = 0; nt < 8; ++nt) {
        float v = (accM[nt][r] + bcol[nt] - mean) * rstd * gcol[nt] + becol[nt];
        atomicAdd(&aggr[(size_t)rr * 128 + nt * 16 + l16], v);
      }
    }
  }

  __syncthreads();
#pragma unroll
  for (int r = 0; r < 4; ++r) {
    float meanE = se[r] * (1.f / 128.f);
    float varE = fmaxf(sse[r] * (1.f / 128.f) - meanE * meanE, 0.f);
    float rstdE = rsqrtf(varE + 1e-5f);
    float meanM = sm[r] * (1.f / 128.f);
    float varM = fmaxf(ssm[r] * (1.f / 128.f) - meanM * meanM, 0.f);
    float rstdM = rsqrtf(varM + 1e-5f);
#pragma unroll
    for (int nt = 0; nt < 8; ++nt) {
      float ve = (accE[nt][r] + bcol[nt] - meanE) * rstdE * gcol[nt] + becol[nt];
      sHe[rowb + r][nt * 16 + l16] = fb(ve);
      if (CSR) {
        float vm = (accM[nt][r] + bcol[nt] - meanM) * rstdM * gcol[nt] + becol[nt];
        sHm[rowb + r][nt * 16 + l16] = fb(vm);
      }
    }
  }
  __syncthreads();

#pragma unroll
  for (int it = 0; it < 4; ++it) {
    int row = prow[it], ch = pch[it];
    int grow = m0 + row;
    if (grow >= E) continue;
    u16 y8[8], e8[8];
    *(uint4*)y8 = *(uint4*)(&sHe[row][ch]);
    *(uint4*)e8 = *(const uint4*)(eh + (size_t)grow * 128 + ch);
#pragma unroll
    for (int j = 0; j < 8; ++j) y8[j] = fb(bl(y8[j]) + bl(e8[j]));
    *(uint4*)(eh + (size_t)grow * 128 + ch) = *(uint4*)y8;

    if (CSR) {
      int rr = sR[row];
      bool first = (row == 0) || (sR[row - 1] != rr);
      if (!first) continue;
      int gs = startp[rr], ge2 = startp[rr + 1];
      int le = ge2 - m0;
      if (le > 64) le = 64;
      float acc[8] = {0, 0, 0, 0, 0, 0, 0, 0};
      for (int i = row; i < le; ++i) {
        u16 m8[8];
        *(uint4*)m8 = *(uint4*)(&sHm[i][ch]);
#pragma unroll
        for (int j = 0; j < 8; ++j) acc[j] += bl(m8[j]);
      }
      if (gs >= m0 && ge2 <= m0 + 64) {
        *(float4*)(aggr + (size_t)rr * 128 + ch) = make_float4(acc[0], acc[1], acc[2], acc[3]);
        *(float4*)(aggr + (size_t)rr * 128 + ch + 4) =
            make_float4(acc[4], acc[5], acc[6], acc[7]);
      } else {
#pragma unroll
        for (int j = 0; j < 8; ++j) atomicAdd(&aggr[(size_t)rr * 128 + ch + j], acc[j]);
      }
    }
  }
}

// decoder: wave per node, 128->64 swish -> 64->5, times dt
__global__ void decoder_kernel(const u16* __restrict__ xh, const float* __restrict__ w1,
                               const float* __restrict__ b1, const float* __restrict__ w2,
                               const float* __restrict__ b2, float* __restrict__ out,
                               int n_nodes) {
  __shared__ float sx[4][128];
  int tid = threadIdx.x;
  int lw = tid >> 6, lane = tid & 63;
  int n0 = blockIdx.x * 4;
  for (int i = tid; i < 512; i += 256) {
    int nn = i >> 7, c = i & 127;
    int n = n0 + nn;
    sx[nn][c] = (n < n_nodes) ? bl(xh[(size_t)n * 128 + c]) : 0.f;
  }
  __syncthreads();
  int n = n0 + lw;
  float h = b1[lane];
#pragma unroll 16
  for (int k = 0; k < 128; ++k) h += sx[lw][k] * w1[k * 64 + lane];
  float hs = h * (1.f / (1.f + __expf(-h)));
  float d[5];
#pragma unroll
  for (int t = 0; t < 5; ++t) {
    float p = hs * w2[lane * 5 + t];
#pragma unroll
    for (int m = 1; m <= 32; m <<= 1) p += __shfl_xor(p, m, 64);
    d[t] = p;
  }
  if (lane == 0 && n < n_nodes) {
#pragma unroll
    for (int t = 0; t < 5; ++t)
      out[(size_t)n * 5 + t] = (float)(t + 1) * (d[t] + b2[t]);
  }
}

extern "C" void kernel_launch(void* const* d_in, const int* in_sizes, int n_in, void* d_out,
                              int out_size, void* d_ws, size_t ws_size, hipStream_t stream) {
  auto F = [&](int i) { return (const float*)d_in[i]; };
  const int* edge_index = (const int*)d_in[6];
  const int N_ = in_sizes[0];
  const int E_ = in_sizes[6] / 2;

  char* wsb = (char*)d_ws;
  size_t off = 0;
  auto alloc = [&](size_t bytes) -> char* {
    char* p = wsb + off;
    off += (bytes + 255) & ~(size_t)255;
    return p;
  };
  u16* xh = (u16*)alloc((size_t)N_ * 128 * 2);
  u16* xhA = (u16*)alloc((size_t)N_ * 128 * 2);
  u16* xhB = (u16*)alloc((size_t)N_ * 128 * 2);
  u16* h1n = (u16*)alloc((size_t)N_ * 128 * 2);
  u16* ehP = (u16*)alloc((size_t)E_ * 128 * 2);
  float* aggr = (float*)alloc((size_t)N_ * 128 * 4);
  float* nfeat = (float*)xhA;  // alias (dead before xhA live)
  float* efeat = (float*)xhB;  // alias
  u16* wne2T = (u16*)alloc(16384 * 2);
  u16* wee2T = (u16*)alloc(16384 * 2);
  u16* wpe1T = (u16*)alloc((size_t)9 * 16384 * 2);
  u16* wpe2T = (u16*)alloc((size_t)3 * 16384 * 2);
  u16* wpn1T = (u16*)alloc((size_t)6 * 16384 * 2);
  u16* wpn2T = (u16*)alloc((size_t)3 * 16384 * 2);

  const size_t base_off = off;
  int* startp = (int*)alloc((size_t)(N_ + 1) * 4);
  int* cntp = (int*)alloc((size_t)N_ * 4);
  int* partp = (int*)alloc((size_t)N_ * 4);
  int* bsump = (int*)alloc(((size_t)(N_ + 255) / 256) * 4 + 256);
  int* sortedS = (int*)alloc((size_t)E_ * 4);
  int* sortedR = (int*)alloc((size_t)E_ * 4);
  bool useCSR = (off <= ws_size);
  if (!useCSR) {
    off = base_off;
    if (off > ws_size) {
      sentinel_kernel<<<(out_size + 255) / 256, 256, 0, stream>>>((float*)d_out, out_size);
      return;
    }
  }

  TArgs ta;
  int ts = 0;
  ta.s[ts++] = {F(13), wne2T};
  ta.s[ts++] = {F(19), wee2T};
  for (int i = 0; i < 3; ++i)
    for (int b = 0; b < 3; ++b)
      ta.s[ts++] = {F(23) + (size_t)(i * 3 + b) * 16384, wpe1T + (size_t)(i * 3 + b) * 16384};
  for (int i = 0; i < 3; ++i) ta.s[ts++] = {F(25) + (size_t)i * 16384, wpe2T + (size_t)i * 16384};
  for (int i = 0; i < 3; ++i)
    for (int b = 0; b < 2; ++b)
      ta.s[ts++] = {F(29) + (size_t)(i * 2 + b) * 16384, wpn1T + (size_t)(i * 2 + b) * 16384};
  for (int i = 0; i < 3; ++i) ta.s[ts++] = {F(31) + (size_t)i * 16384, wpn2T + (size_t)i * 16384};

  const int tilesN = (N_ + 63) / 64;
  const int tilesE = (E_ + 63) / 64;
  const int nb = (N_ + 255) / 256;
  dim3 blk(256);

  transpose_w<<<23, blk, 0, stream>>>(ta);

  const int* sArr = edge_index;
  const int* rArr = edge_index + E_;
  if (useCSR) {
    zero_i32<<<(N_ + 255) / 256, blk, 0, stream>>>(cntp, N_);
    deg_count<<<(E_ + 255) / 256, blk, 0, stream>>>(edge_index, cntp, E_);
    scan1<<<nb, blk, 0, stream>>>(cntp, partp, bsump, N_);
    scan2<<<1, blk, 0, stream>>>(bsump, nb);
    scan3<<<nb, blk, 0, stream>>>(partp, bsump, startp, N_);
    zero_i32<<<(N_ + 255) / 256, blk, 0, stream>>>(cntp, N_);
    fill_slot<<<(E_ + 255) / 256, blk, 0, stream>>>(edge_index, cntp, startp, sortedS, sortedR,
                                                    E_);
    sArr = sortedS;
    rArr = sortedR;
  }

  // ---- encode ----
  node_feat_kernel<<<(N_ + 255) / 256, blk, 0, stream>>>(F(0), F(1), F(2), F(3), F(4), F(7),
                                                         F(8), nfeat, N_);
  enc1_kernel<9><<<(N_ * 128 + 255) / 256, blk, 0, stream>>>(nfeat, F(11), F(12), h1n, N_);
  gemm64<GM_LN, false, false><<<tilesN, blk, 0, stream>>>(h1n, wne2T, nullptr, nullptr, F(14),
                                                          F(15), F(16), nullptr, xh, N_);
  edge_feat_kernel<<<(E_ + 255) / 256, blk, 0, stream>>>(sArr, rArr, F(5), F(0), F(9), F(10),
                                                         efeat, E_);
  enc1_kernel<4><<<(E_ * 128 + 255) / 256, blk, 0, stream>>>(efeat, F(17), F(18), ehP, E_);
  gemm64<GM_LN, false, false><<<tilesE, blk, 0, stream>>>(ehP, wee2T, nullptr, nullptr, F(20),
                                                          F(21), F(22), nullptr, ehP, E_);

  // ---- process steps ----
  for (int i = 0; i < 3; ++i) {
    const u16* wtA = wpe1T + (size_t)(i * 3 + 0) * 16384;
    const u16* wtB = wpe1T + (size_t)(i * 3 + 1) * 16384;
    const u16* wtC = wpe1T + (size_t)(i * 3 + 2) * 16384;
    const float* pb1 = F(24) + i * 128;
    const u16* wt2 = wpe2T + (size_t)i * 16384;
    const float* pb2 = F(26) + i * 128;
    const float* pg = F(27) + i * 128;
    const float* pbe = F(28) + i * 128;
    const u16* wtnA = wpn1T + (size_t)(i * 2 + 0) * 16384;
    const u16* wtnB = wpn1T + (size_t)(i * 2 + 1) * 16384;
    const float* nb1 = F(30) + i * 128;
    const u16* wtn2 = wpn2T + (size_t)i * 16384;
    const float* nb2 = F(32) + i * 128;
    const float* ng = F(33) + i * 128;
    const float* nbe = F(34) + i * 128;

    if (i == 0)
      gemm64_2w<<<tilesN, blk, 0, stream>>>(xh, wtA, wtB, xhA, xhB, aggr, N_);
    if (useCSR) {
      edge_fused<true><<<tilesE, blk, 0, stream>>>(ehP, xhA, xhB, wtC, pb1, wt2, pb2, pg, pbe,
                                                   sArr, rArr, startp, aggr, E_);
    } else {
      edge_fused<false><<<tilesE, blk, 0, stream>>>(ehP, xhA, xhB, wtC, pb1, wt2, pb2, pg, pbe,
                                                    sArr, rArr, nullptr, aggr, E_);
    }
    const u16* wtA2 = (i < 2) ? wpe1T + (size_t)((i + 1) * 3 + 0) * 16384 : nullptr;
    const u16* wtB2 = (i < 2) ? wpe1T + (size_t)((i + 1) * 3 + 1) * 16384 : nullptr;
    node_fused_2w<<<tilesN, blk, 0, stream>>>(xh, aggr, wtnA, wtnB, nb1, wtn2, nb2, ng, nbe,
                                              wtA2, wtB2, xhA, xhB, N_);
  }

  // ---- decode ----
  decoder_kernel<<<(N_ + 3) / 4, blk, 0, stream>>>(xh, F(35), F(36), F(37), F(38),
                                                   (float*)d_out, N_);
}

// Round 18
// 1217.664 us; speedup vs baseline: 1.2495x; 1.0666x over previous
//
#include <hip/hip_runtime.h>
#include <stdint.h>

typedef unsigned short u16;
typedef __attribute__((ext_vector_type(8))) short bf16x8_t;
typedef __attribute__((ext_vector_type(4))) float f32x4_t;

__device__ __forceinline__ float bl(u16 x) {
  union { unsigned u; float f; } c; c.u = ((unsigned)x) << 16; return c.f;
}
__device__ __forceinline__ u16 fb(float x) {
  union { float f; unsigned u; } c; c.f = x;
  unsigned r = c.u + 0x7fffu + ((c.u >> 16) & 1u);
  return (u16)(r >> 16);
}

__global__ void sentinel_kernel(float* out, int n) {
  int i = blockIdx.x * 256 + threadIdx.x;
  if (i < n) out[i] = 12345.f;
}

// ---------------- weight transpose: wT[n][k] = fb(W[k][n]) ----------------
struct TSeg { const float* src; u16* dst; };
struct TArgs { TSeg s[23]; };
__global__ void transpose_w(TArgs a) {
  const float* src = a.s[blockIdx.x].src;
  u16* dst = a.s[blockIdx.x].dst;
  for (int e = threadIdx.x; e < 16384; e += 256) {
    int n = e >> 7, k = e & 127;
    dst[e] = fb(src[k * 128 + n]);
  }
}

// ---------------- CSR build + receiver-sort ----------------
__global__ void zero_i32(int* p, int n) {
  int i = blockIdx.x * 256 + threadIdx.x;
  if (i < n) p[i] = 0;
}
__global__ void deg_count(const int* __restrict__ ei, int* __restrict__ cnt, int E) {
  int e = blockIdx.x * 256 + threadIdx.x;
  if (e < E) atomicAdd(&cnt[ei[E + e]], 1);
}
__global__ void scan1(const int* __restrict__ cnt, int* __restrict__ part,
                      int* __restrict__ bsum, int N) {
  __shared__ int s[256];
  int i = blockIdx.x * 256 + threadIdx.x;
  s[threadIdx.x] = (i < N) ? cnt[i] : 0;
  __syncthreads();
#pragma unroll
  for (int o = 1; o < 256; o <<= 1) {
    int t = (threadIdx.x >= o) ? s[threadIdx.x - o] : 0;
    __syncthreads();
    s[threadIdx.x] += t;
    __syncthreads();
  }
  if (i < N) part[i] = s[threadIdx.x];
  if (threadIdx.x == 255) bsum[blockIdx.x] = s[255];
}
__global__ void scan2(int* bsum, int nb) {
  if (threadIdx.x == 0 && blockIdx.x == 0) {
    int acc = 0;
    for (int i = 0; i < nb; ++i) { int t = bsum[i]; bsum[i] = acc; acc += t; }
  }
}
__global__ void scan3(const int* __restrict__ part, const int* __restrict__ bsum,
                      int* __restrict__ start, int N) {
  int i = blockIdx.x * 256 + threadIdx.x;
  if (i < N) start[i + 1] = part[i] + bsum[i >> 8];
  if (i == 0) start[0] = 0;
}
__global__ void fill_slot(const int* __restrict__ ei, int* __restrict__ cnt2,
                          const int* __restrict__ start, int* __restrict__ sortedS,
                          int* __restrict__ sortedR, int E) {
  int e = blockIdx.x * 256 + threadIdx.x;
  if (e >= E) return;
  int s = ei[e], r = ei[E + e];
  int p = atomicAdd(&cnt2[r], 1);
  int slot = start[r] + p;
  sortedS[slot] = s;
  sortedR[slot] = r;
}

// ---------------- feature kernels ----------------
__global__ void node_feat_kernel(const float* __restrict__ t, const float* __restrict__ tp,
                                 const float* __restrict__ q, const float* __restrict__ qp,
                                 const float* __restrict__ qn, const float* __restrict__ nm,
                                 const float* __restrict__ ns, float* __restrict__ nfeat,
                                 int n_nodes) {
  int n = blockIdx.x * 256 + threadIdx.x;
  if (n >= n_nodes) return;
  float u = t[n];
  float x[9];
  x[0] = u; x[1] = u - tp[n];
  float hq = q[n];
  x[2] = hq; x[3] = hq - qp[n];
#pragma unroll
  for (int j = 0; j < 5; ++j) x[4 + j] = qn[n * 5 + j];
#pragma unroll
  for (int k = 0; k < 9; ++k) nfeat[n * 9 + k] = (x[k] - nm[k]) / ns[k];
}

__global__ void edge_feat_kernel(const int* __restrict__ sArr, const int* __restrict__ rArr,
                                 const float* __restrict__ mp, const float* __restrict__ u,
                                 const float* __restrict__ em, const float* __restrict__ es,
                                 float* __restrict__ efeat, int n_edges) {
  int e = blockIdx.x * 256 + threadIdx.x;
  if (e >= n_edges) return;
  int s = sArr[e], r = rArr[e];
  float rx = mp[s * 2] - mp[r * 2];
  float ry = mp[s * 2 + 1] - mp[r * 2 + 1];
  float d = sqrtf(rx * rx + ry * ry);
  float rt = u[s] - u[r];
  float x[4] = {rx, ry, d, rt};
#pragma unroll
  for (int k = 0; k < 4; ++k) efeat[e * 4 + k] = (x[k] - em[k]) / es[k];
}

// ---------------- fused encoder: LN(relu(feat@W1+b1)@W2+b2) -> out ----------------
template <int K>
__global__ __launch_bounds__(256, 2) void encode_fused(
    const float* __restrict__ feat, const float* __restrict__ w1f, const float* __restrict__ b1f,
    const u16* __restrict__ wt2, const float* __restrict__ b2, const float* __restrict__ gg,
    const float* __restrict__ bb, u16* __restrict__ out, int M) {
  __shared__ float sW1[K * 128];
  __shared__ float sB1[128];
  __shared__ u16 sH[64][136];
  const int tid = threadIdx.x;
  const int wave = tid >> 6, lane = tid & 63;
  const int q = lane >> 4, l16 = lane & 15;
  const int m0 = blockIdx.x * 64;
  const int rowb = wave * 16 + q * 4;
  const int arow = m0 + wave * 16 + l16;
  const int arc = arow < M ? arow : M - 1;

  for (int i = tid; i < K * 128; i += 256) sW1[i] = w1f[i];
  if (tid < 128) sB1[tid] = b1f[tid];
  __syncthreads();

  float fr[K];
#pragma unroll
  for (int k = 0; k < K; ++k) fr[k] = feat[(size_t)arc * K + k];

  // per-lane h1 fragment (A-layout) + MFMA with W2^T
  f32x4_t acc[8];
#pragma unroll
  for (int b = 0; b < 8; ++b) acc[b] = (f32x4_t){0.f, 0.f, 0.f, 0.f};
#pragma unroll
  for (int kk = 0; kk < 4; ++kk) {
    union { u16 u[8]; bf16x8_t v; } cv;
#pragma unroll
    for (int j = 0; j < 8; ++j) {
      int col = kk * 32 + q * 8 + j;
      float h = sB1[col];
#pragma unroll
      for (int k = 0; k < K; ++k) h += fr[k] * sW1[k * 128 + col];
      cv.u[j] = fb(h > 0.f ? h : 0.f);
    }
#pragma unroll
    for (int nt = 0; nt < 8; ++nt) {
      bf16x8_t bfv = *(const bf16x8_t*)(wt2 + (size_t)(nt * 16 + l16) * 128 + kk * 32 + q * 8);
      acc[nt] = __builtin_amdgcn_mfma_f32_16x16x32_bf16(cv.v, bfv, acc[nt], 0, 0, 0);
    }
  }

  // LN epilogue
  float bcol[8], gcol[8], becol[8];
#pragma unroll
  for (int nt = 0; nt < 8; ++nt) {
    bcol[nt] = b2[nt * 16 + l16];
    gcol[nt] = gg[nt * 16 + l16];
    becol[nt] = bb[nt * 16 + l16];
  }
  float s[4] = {0, 0, 0, 0}, ss[4] = {0, 0, 0, 0};
#pragma unroll
  for (int r = 0; r < 4; ++r)
#pragma unroll
    for (int nt = 0; nt < 8; ++nt) {
      float v = acc[nt][r] + bcol[nt];
      s[r] += v;
      ss[r] += v * v;
    }
#pragma unroll
  for (int r = 0; r < 4; ++r) {
#pragma unroll
    for (int m = 1; m <= 8; m <<= 1) {
      s[r] += __shfl_xor(s[r], m, 64);
      ss[r] += __shfl_xor(ss[r], m, 64);
    }
  }
#pragma unroll
  for (int r = 0; r < 4; ++r) {
    float mean = s[r] * (1.f / 128.f);
    float var = fmaxf(ss[r] * (1.f / 128.f) - mean * mean, 0.f);
    float rstd = rsqrtf(var + 1e-5f);
#pragma unroll
    for (int nt = 0; nt < 8; ++nt) {
      float v = (acc[nt][r] + bcol[nt] - mean) * rstd * gcol[nt] + becol[nt];
      sH[rowb + r][nt * 16 + l16] = fb(v);
    }
  }
  __syncthreads();
#pragma unroll
  for (int it = 0; it < 4; ++it) {
    int lin = it * 256 + tid;
    int row = lin >> 4, ch = (lin & 15) * 8;
    int grow = m0 + row;
    if (grow >= M) continue;
    *(uint4*)(out + (size_t)grow * 128 + ch) = *(uint4*)(&sH[row][ch]);
  }
}

// dual-output GEMM: out0 = A@W0, out1 = A@W1 (A read once); also zeroes aggr rows
__global__ __launch_bounds__(256, 2) void gemm64_2w(
    const u16* __restrict__ A, const u16* __restrict__ WT0, const u16* __restrict__ WT1,
    u16* __restrict__ out0, u16* __restrict__ out1, float* __restrict__ aggr, int M) {
  __shared__ u16 sO0[64][136];
  __shared__ u16 sO1[64][136];
  const int tid = threadIdx.x;
  const int wave = tid >> 6, lane = tid & 63;
  const int q = lane >> 4, l16 = lane & 15;
  const int m0 = blockIdx.x * 64;
  int arow = m0 + wave * 16 + l16;
  if (arow >= M) arow = M - 1;

  {
    float4 z = make_float4(0.f, 0.f, 0.f, 0.f);
#pragma unroll
    for (int it = 0; it < 8; ++it) {
      int lin = it * 256 + tid;
      int row = lin >> 5, c4 = (lin & 31) * 4;
      int grow = m0 + row;
      if (grow < M) *(float4*)(aggr + (size_t)grow * 128 + c4) = z;
    }
  }

  f32x4_t a0[8], a1[8];
#pragma unroll
  for (int b = 0; b < 8; ++b) {
    a0[b] = (f32x4_t){0.f, 0.f, 0.f, 0.f};
    a1[b] = (f32x4_t){0.f, 0.f, 0.f, 0.f};
  }
#pragma unroll 2
  for (int kk = 0; kk < 4; ++kk) {
    bf16x8_t af = *(const bf16x8_t*)(A + (size_t)arow * 128 + kk * 32 + q * 8);
#pragma unroll
    for (int nt = 0; nt < 8; ++nt) {
      bf16x8_t b0 = *(const bf16x8_t*)(WT0 + (size_t)(nt * 16 + l16) * 128 + kk * 32 + q * 8);
      bf16x8_t b1v = *(const bf16x8_t*)(WT1 + (size_t)(nt * 16 + l16) * 128 + kk * 32 + q * 8);
      a0[nt] = __builtin_amdgcn_mfma_f32_16x16x32_bf16(af, b0, a0[nt], 0, 0, 0);
      a1[nt] = __builtin_amdgcn_mfma_f32_16x16x32_bf16(af, b1v, a1[nt], 0, 0, 0);
    }
  }
  const int rowb = wave * 16 + q * 4;
#pragma unroll
  for (int r = 0; r < 4; ++r)
#pragma unroll
    for (int nt = 0; nt < 8; ++nt) {
      sO0[rowb + r][nt * 16 + l16] = fb(a0[nt][r]);
      sO1[rowb + r][nt * 16 + l16] = fb(a1[nt][r]);
    }
  __syncthreads();
#pragma unroll
  for (int it = 0; it < 4; ++it) {
    int lin = it * 256 + tid;
    int row = lin >> 4, ch = (lin & 15) * 8;
    int grow = m0 + row;
    if (grow >= M) continue;
    *(uint4*)(out0 + (size_t)grow * 128 + ch) = *(uint4*)(&sO0[row][ch]);
    *(uint4*)(out1 + (size_t)grow * 128 + ch) = *(uint4*)(&sO1[row][ch]);
  }
}

// ---------------- fused node-update (+ next-step dual GEMM) ----------------
__global__ __launch_bounds__(256, 2) void node_fused_2w(
    u16* __restrict__ xh, float* __restrict__ aggr, const u16* __restrict__ wtA,
    const u16* __restrict__ wtB, const float* __restrict__ b1, const u16* __restrict__ wt2,
    const float* __restrict__ b2, const float* __restrict__ gg, const float* __restrict__ bb,
    const u16* __restrict__ wtA2, const u16* __restrict__ wtB2, u16* __restrict__ xhA,
    u16* __restrict__ xhB, int M) {
  __shared__ u16 sH[64][136];
  __shared__ u16 sO1[64][136];
  const int tid = threadIdx.x;
  const int wave = tid >> 6, lane = tid & 63;
  const int q = lane >> 4, l16 = lane & 15;
  const int m0 = blockIdx.x * 64;
  const int rowb = wave * 16 + q * 4;
  const int arow = m0 + wave * 16 + l16;
  const int arc = arow < M ? arow : M - 1;

  bf16x8_t xf[4], af_[4];
#pragma unroll
  for (int kk = 0; kk < 4; ++kk) {
    xf[kk] = *(const bf16x8_t*)(xh + (size_t)arc * 128 + kk * 32 + q * 8);
    const float* ap = aggr + (size_t)arc * 128 + kk * 32 + q * 8;
    union { u16 u[8]; bf16x8_t v; } cv;
#pragma unroll
    for (int j = 0; j < 8; ++j) cv.u[j] = fb(ap[j]);
    af_[kk] = cv.v;
  }

  f32x4_t acc[8];
#pragma unroll
  for (int b = 0; b < 8; ++b) acc[b] = (f32x4_t){0.f, 0.f, 0.f, 0.f};
#pragma unroll
  for (int kk = 0; kk < 4; ++kk) {
#pragma unroll
    for (int nt = 0; nt < 8; ++nt) {
      bf16x8_t bA = *(const bf16x8_t*)(wtA + (size_t)(nt * 16 + l16) * 128 + kk * 32 + q * 8);
      bf16x8_t bB = *(const bf16x8_t*)(wtB + (size_t)(nt * 16 + l16) * 128 + kk * 32 + q * 8);
      acc[nt] = __builtin_amdgcn_mfma_f32_16x16x32_bf16(af_[kk], bA, acc[nt], 0, 0, 0);
      acc[nt] = __builtin_amdgcn_mfma_f32_16x16x32_bf16(xf[kk], bB, acc[nt], 0, 0, 0);
    }
  }
  float bcol1[8];
#pragma unroll
  for (int nt = 0; nt < 8; ++nt) bcol1[nt] = b1[nt * 16 + l16];
#pragma unroll
  for (int r = 0; r < 4; ++r)
#pragma unroll
    for (int nt = 0; nt < 8; ++nt) {
      float v = acc[nt][r] + bcol1[nt];
      sH[rowb + r][nt * 16 + l16] = fb(v > 0.f ? v : 0.f);
    }
  __syncthreads();

  f32x4_t acc2[8];
#pragma unroll
  for (int b = 0; b < 8; ++b) acc2[b] = (f32x4_t){0.f, 0.f, 0.f, 0.f};
#pragma unroll
  for (int kk = 0; kk < 4; ++kk) {
    bf16x8_t afm = *(const bf16x8_t*)(&sH[wave * 16 + l16][kk * 32 + q * 8]);
#pragma unroll
    for (int nt = 0; nt < 8; ++nt) {
      bf16x8_t bfv = *(const bf16x8_t*)(wt2 + (size_t)(nt * 16 + l16) * 128 + kk * 32 + q * 8);
      acc2[nt] = __builtin_amdgcn_mfma_f32_16x16x32_bf16(afm, bfv, acc2[nt], 0, 0, 0);
    }
  }
  float bcol[8], gcol[8], becol[8];
#pragma unroll
  for (int nt = 0; nt < 8; ++nt) {
    bcol[nt] = b2[nt * 16 + l16];
    gcol[nt] = gg[nt * 16 + l16];
    becol[nt] = bb[nt * 16 + l16];
  }
  float s[4] = {0, 0, 0, 0}, ss[4] = {0, 0, 0, 0};
#pragma unroll
  for (int r = 0; r < 4; ++r)
#pragma unroll
    for (int nt = 0; nt < 8; ++nt) {
      float v = acc2[nt][r] + bcol[nt];
      s[r] += v;
      ss[r] += v * v;
    }
#pragma unroll
  for (int r = 0; r < 4; ++r) {
#pragma unroll
    for (int m = 1; m <= 8; m <<= 1) {
      s[r] += __shfl_xor(s[r], m, 64);
      ss[r] += __shfl_xor(ss[r], m, 64);
    }
  }
  __syncthreads();
#pragma unroll
  for (int r = 0; r < 4; ++r) {
    float mean = s[r] * (1.f / 128.f);
    float var = fmaxf(ss[r] * (1.f / 128.f) - mean * mean, 0.f);
    float rstd = rsqrtf(var + 1e-5f);
#pragma unroll
    for (int nt = 0; nt < 8; ++nt) {
      float v = (acc2[nt][r] + bcol[nt] - mean) * rstd * gcol[nt] + becol[nt];
      sH[rowb + r][nt * 16 + l16] = fb(v);
    }
  }
  __syncthreads();

  bf16x8_t nf[4];
#pragma unroll
  for (int kk = 0; kk < 4; ++kk) {
    u16 y8[8];
    *(uint4*)y8 = *(uint4*)(&sH[wave * 16 + l16][kk * 32 + q * 8]);
#pragma unroll
    for (int j = 0; j < 8; ++j) y8[j] = fb(bl(y8[j]) + bl((u16)xf[kk][j]));
    nf[kk] = *(bf16x8_t*)y8;
    if (arow < M)
      *(uint4*)(xh + (size_t)arow * 128 + kk * 32 + q * 8) = *(uint4*)y8;
  }

  if (wtA2 == nullptr) return;

  if (arow < M) {
    float4 z = make_float4(0.f, 0.f, 0.f, 0.f);
#pragma unroll
    for (int kk = 0; kk < 4; ++kk) {
      *(float4*)(aggr + (size_t)arow * 128 + kk * 32 + q * 8) = z;
      *(float4*)(aggr + (size_t)arow * 128 + kk * 32 + q * 8 + 4) = z;
    }
  }

  f32x4_t a0[8], a1[8];
#pragma unroll
  for (int b = 0; b < 8; ++b) {
    a0[b] = (f32x4_t){0.f, 0.f, 0.f, 0.f};
    a1[b] = (f32x4_t){0.f, 0.f, 0.f, 0.f};
  }
#pragma unroll
  for (int kk = 0; kk < 4; ++kk) {
#pragma unroll
    for (int nt = 0; nt < 8; ++nt) {
      bf16x8_t b0 = *(const bf16x8_t*)(wtA2 + (size_t)(nt * 16 + l16) * 128 + kk * 32 + q * 8);
      bf16x8_t b1v = *(const bf16x8_t*)(wtB2 + (size_t)(nt * 16 + l16) * 128 + kk * 32 + q * 8);
      a0[nt] = __builtin_amdgcn_mfma_f32_16x16x32_bf16(nf[kk], b0, a0[nt], 0, 0, 0);
      a1[nt] = __builtin_amdgcn_mfma_f32_16x16x32_bf16(nf[kk], b1v, a1[nt], 0, 0, 0);
    }
  }
  __syncthreads();
#pragma unroll
  for (int r = 0; r < 4; ++r)
#pragma unroll
    for (int nt = 0; nt < 8; ++nt) {
      sH[rowb + r][nt * 16 + l16] = fb(a0[nt][r]);
      sO1[rowb + r][nt * 16 + l16] = fb(a1[nt][r]);
    }
  __syncthreads();
#pragma unroll
  for (int it = 0; it < 4; ++it) {
    int lin = it * 256 + tid;
    int row = lin >> 4, ch = (lin & 15) * 8;
    int grow = m0 + row;
    if (grow >= M) continue;
    *(uint4*)(xhA + (size_t)grow * 128 + ch) = *(uint4*)(&sH[row][ch]);
    *(uint4*)(xhB + (size_t)grow * 128 + ch) = *(uint4*)(&sO1[row][ch]);
  }
}

// ---------------- fused edge kernel (round-12 champion) ----------------
template <bool CSR>
__global__ __launch_bounds__(256, 2) void edge_fused(
    u16* __restrict__ eh, const u16* __restrict__ xhA, const u16* __restrict__ xhB,
    const u16* __restrict__ wtC, const float* __restrict__ b1, const u16* __restrict__ wt2,
    const float* __restrict__ b2, const float* __restrict__ gg, const float* __restrict__ bb,
    const int* __restrict__ sArr, const int* __restrict__ rArr,
    const int* __restrict__ startp, float* __restrict__ aggr, int E) {
  __shared__ u16 sHm[64][136];
  __shared__ u16 sHe[64][136];
  __shared__ int sR[64];
  const int tid = threadIdx.x;
  const int wave = tid >> 6, lane = tid & 63;
  const int q = lane >> 4, l16 = lane & 15;
  const int m0 = blockIdx.x * 64;
  const int rowb = wave * 16 + q * 4;
  int arow = m0 + wave * 16 + l16;
  int arc = arow < E ? arow : E - 1;

  if (tid < 64) {
    int e = m0 + tid;
    sR[tid] = (e < E) ? rArr[e] : -1;
  }

  int prow[4], pch[4], pr_[4];
  uint4 pAs[4], pBs[4];
#pragma unroll
  for (int it = 0; it < 4; ++it) {
    int lin = it * 256 + tid;
    prow[it] = lin >> 4;
    pch[it] = (lin & 15) * 8;
    int ge = m0 + prow[it];
    int gc = ge < E ? ge : E - 1;
    int ps = sArr[gc];
    pr_[it] = rArr[gc];
    pAs[it] = *(const uint4*)(xhA + (size_t)ps * 128 + pch[it]);
    pBs[it] = *(const uint4*)(xhB + (size_t)ps * 128 + pch[it]);
  }
  bf16x8_t ehf[4];
#pragma unroll
  for (int kk = 0; kk < 4; ++kk)
    ehf[kk] = *(const bf16x8_t*)(eh + (size_t)arc * 128 + kk * 32 + q * 8);

  f32x4_t accC[8];
#pragma unroll
  for (int b = 0; b < 8; ++b) accC[b] = (f32x4_t){0.f, 0.f, 0.f, 0.f};
#pragma unroll
  for (int kk = 0; kk < 4; ++kk) {
#pragma unroll
    for (int nt = 0; nt < 8; ++nt) {
      bf16x8_t bfv = *(const bf16x8_t*)(wtC + (size_t)(nt * 16 + l16) * 128 + kk * 32 + q * 8);
      accC[nt] = __builtin_amdgcn_mfma_f32_16x16x32_bf16(ehf[kk], bfv, accC[nt], 0, 0, 0);
    }
  }
#pragma unroll
  for (int r = 0; r < 4; ++r)
#pragma unroll
    for (int nt = 0; nt < 8; ++nt) sHm[rowb + r][nt * 16 + l16] = fb(accC[nt][r]);
  __syncthreads();

#pragma unroll
  for (int it = 0; it < 4; ++it) {
    int row = prow[it], ch = pch[it];
    bool ok = (m0 + row) < E;
    int r_ = pr_[it] >= 0 ? pr_[it] : 0;
    u16 t8[8], ar[8], as_[8], br[8], bs[8], hm[8], he[8];
    *(uint4*)t8 = *(uint4*)(&sHm[row][ch]);
    *(uint4*)ar = *(const uint4*)(xhA + (size_t)r_ * 128 + ch);
    *(uint4*)br = *(const uint4*)(xhB + (size_t)r_ * 128 + ch);
    *(uint4*)as_ = pAs[it];
    *(uint4*)bs = pBs[it];
#pragma unroll
    for (int j = 0; j < 8; ++j) {
      float t = bl(t8[j]) + b1[ch + j];
      float vm = t + bl(ar[j]) + bl(bs[j]);
      float ve = t + bl(as_[j]) + bl(br[j]);
      hm[j] = (ok && vm > 0.f) ? fb(vm) : 0;
      he[j] = (ok && ve > 0.f) ? fb(ve) : 0;
    }
    *(uint4*)(&sHm[row][ch]) = *(uint4*)hm;
    *(uint4*)(&sHe[row][ch]) = *(uint4*)he;
  }
  __syncthreads();

  float bcol[8], gcol[8], becol[8];
#pragma unroll
  for (int nt = 0; nt < 8; ++nt) {
    bcol[nt] = b2[nt * 16 + l16];
    gcol[nt] = gg[nt * 16 + l16];
    becol[nt] = bb[nt * 16 + l16];
  }

  f32x4_t accM[8], accE[8];
#pragma unroll
  for (int b = 0; b < 8; ++b) {
    accM[b] = (f32x4_t){0.f, 0.f, 0.f, 0.f};
    accE[b] = (f32x4_t){0.f, 0.f, 0.f, 0.f};
  }
#pragma unroll
  for (int kk = 0; kk < 4; ++kk) {
    bf16x8_t afm = *(const bf16x8_t*)(&sHm[wave * 16 + l16][kk * 32 + q * 8]);
    bf16x8_t afe = *(const bf16x8_t*)(&sHe[wave * 16 + l16][kk * 32 + q * 8]);
#pragma unroll
    for (int nt = 0; nt < 8; ++nt) {
      bf16x8_t bfv = *(const bf16x8_t*)(wt2 + (size_t)(nt * 16 + l16) * 128 + kk * 32 + q * 8);
      accM[nt] = __builtin_amdgcn_mfma_f32_16x16x32_bf16(afm, bfv, accM[nt], 0, 0, 0);
      accE[nt] = __builtin_amdgcn_mfma_f32_16x16x32_bf16(afe, bfv, accE[nt], 0, 0, 0);
    }
  }
  float sm[4] = {0, 0, 0, 0}, ssm[4] = {0, 0, 0, 0};
  float se[4] = {0, 0, 0, 0}, sse[4] = {0, 0, 0, 0};
#pragma unroll
  for (int r = 0; r < 4; ++r)
#pragma unroll
    for (int nt = 0; nt < 8; ++nt) {
      float vm = accM[nt][r] + bcol[nt];
      float ve = accE[nt][r] + bcol[nt];
      sm[r] += vm; ssm[r] += vm * vm;
      se[r] += ve; sse[r] += ve * ve;
    }
#pragma unroll
  for (int r = 0; r < 4; ++r) {
#pragma unroll
    for (int m = 1; m <= 8; m <<= 1) {
      sm[r] += __shfl_xor(sm[r], m, 64);
      ssm[r] += __shfl_xor(ssm[r], m, 64);
      se[r] += __shfl_xor(se[r], m, 64);
      sse[r] += __shfl_xor(sse[r], m, 64);
    }
  }

  if (!CSR) {
#pragma unroll
    for (int r = 0; r < 4; ++r) {
      int row = m0 + rowb + r;
      if (row >= E) continue;
      int rr = sR[rowb + r];
      float mean = sm[r] * (1.f / 128.f);
      float var = fmaxf(ssm[r] * (1.f / 128.f) - mean * mean, 0.f);
      float rstd = rsqrtf(var + 1e-5f);
#pragma unroll
      for (int nt = 0; nt < 8; ++nt) {
        float v = (accM[nt][r] + bcol[nt] - mean) * rstd * gcol[nt] + becol[nt];
        atomicAdd(&aggr[(size_t)rr * 128 + nt * 16 + l16], v);
      }
    }
  }

  __syncthreads();
#pragma unroll
  for (int r = 0; r < 4; ++r) {
    float meanE = se[r] * (1.f / 128.f);
    float varE = fmaxf(sse[r] * (1.f / 128.f) - meanE * meanE, 0.f);
    float rstdE = rsqrtf(varE + 1e-5f);
    float meanM = sm[r] * (1.f / 128.f);
    float varM = fmaxf(ssm[r] * (1.f / 128.f) - meanM * meanM, 0.f);
    float rstdM = rsqrtf(varM + 1e-5f);
#pragma unroll
    for (int nt = 0; nt < 8; ++nt) {
      float ve = (accE[nt][r] + bcol[nt] - meanE) * rstdE * gcol[nt] + becol[nt];
      sHe[rowb + r][nt * 16 + l16] = fb(ve);
      if (CSR) {
        float vm = (accM[nt][r] + bcol[nt] - meanM) * rstdM * gcol[nt] + becol[nt];
        sHm[rowb + r][nt * 16 + l16] = fb(vm);
      }
    }
  }
  __syncthreads();

#pragma unroll
  for (int it = 0; it < 4; ++it) {
    int row = prow[it], ch = pch[it];
    int grow = m0 + row;
    if (grow >= E) continue;
    u16 y8[8], e8[8];
    *(uint4*)y8 = *(uint4*)(&sHe[row][ch]);
    *(uint4*)e8 = *(const uint4*)(eh + (size_t)grow * 128 + ch);
#pragma unroll
    for (int j = 0; j < 8; ++j) y8[j] = fb(bl(y8[j]) + bl(e8[j]));
    *(uint4*)(eh + (size_t)grow * 128 + ch) = *(uint4*)y8;

    if (CSR) {
      int rr = sR[row];
      bool first = (row == 0) || (sR[row - 1] != rr);
      if (!first) continue;
      int gs = startp[rr], ge2 = startp[rr + 1];
      int le = ge2 - m0;
      if (le > 64) le = 64;
      float acc[8] = {0, 0, 0, 0, 0, 0, 0, 0};
      for (int i = row; i < le; ++i) {
        u16 m8[8];
        *(uint4*)m8 = *(uint4*)(&sHm[i][ch]);
#pragma unroll
        for (int j = 0; j < 8; ++j) acc[j] += bl(m8[j]);
      }
      if (gs >= m0 && ge2 <= m0 + 64) {
        *(float4*)(aggr + (size_t)rr * 128 + ch) = make_float4(acc[0], acc[1], acc[2], acc[3]);
        *(float4*)(aggr + (size_t)rr * 128 + ch + 4) =
            make_float4(acc[4], acc[5], acc[6], acc[7]);
      } else {
#pragma unroll
        for (int j = 0; j < 8; ++j) atomicAdd(&aggr[(size_t)rr * 128 + ch + j], acc[j]);
      }
    }
  }
}

// decoder: wave per node, 128->64 swish -> 64->5, times dt
__global__ void decoder_kernel(const u16* __restrict__ xh, const float* __restrict__ w1,
                               const float* __restrict__ b1, const float* __restrict__ w2,
                               const float* __restrict__ b2, float* __restrict__ out,
                               int n_nodes) {
  __shared__ float sx[4][128];
  int tid = threadIdx.x;
  int lw = tid >> 6, lane = tid & 63;
  int n0 = blockIdx.x * 4;
  for (int i = tid; i < 512; i += 256) {
    int nn = i >> 7, c = i & 127;
    int n = n0 + nn;
    sx[nn][c] = (n < n_nodes) ? bl(xh[(size_t)n * 128 + c]) : 0.f;
  }
  __syncthreads();
  int n = n0 + lw;
  float h = b1[lane];
#pragma unroll 16
  for (int k = 0; k < 128; ++k) h += sx[lw][k] * w1[k * 64 + lane];
  float hs = h * (1.f / (1.f + __expf(-h)));
  float d[5];
#pragma unroll
  for (int t = 0; t < 5; ++t) {
    float p = hs * w2[lane * 5 + t];
#pragma unroll
    for (int m = 1; m <= 32; m <<= 1) p += __shfl_xor(p, m, 64);
    d[t] = p;
  }
  if (lane == 0 && n < n_nodes) {
#pragma unroll
    for (int t = 0; t < 5; ++t)
      out[(size_t)n * 5 + t] = (float)(t + 1) * (d[t] + b2[t]);
  }
}

extern "C" void kernel_launch(void* const* d_in, const int* in_sizes, int n_in, void* d_out,
                              int out_size, void* d_ws, size_t ws_size, hipStream_t stream) {
  auto F = [&](int i) { return (const float*)d_in[i]; };
  const int* edge_index = (const int*)d_in[6];
  const int N_ = in_sizes[0];
  const int E_ = in_sizes[6] / 2;

  char* wsb = (char*)d_ws;
  size_t off = 0;
  auto alloc = [&](size_t bytes) -> char* {
    char* p = wsb + off;
    off += (bytes + 255) & ~(size_t)255;
    return p;
  };
  u16* xh = (u16*)alloc((size_t)N_ * 128 * 2);
  u16* xhA = (u16*)alloc((size_t)N_ * 128 * 2);
  u16* xhB = (u16*)alloc((size_t)N_ * 128 * 2);
  u16* ehP = (u16*)alloc((size_t)E_ * 128 * 2);
  float* aggr = (float*)alloc((size_t)N_ * 128 * 4);
  float* nfeat = (float*)xhA;  // alias (dead before xhA live)
  float* efeat = (float*)xhB;  // alias
  u16* wne2T = (u16*)alloc(16384 * 2);
  u16* wee2T = (u16*)alloc(16384 * 2);
  u16* wpe1T = (u16*)alloc((size_t)9 * 16384 * 2);
  u16* wpe2T = (u16*)alloc((size_t)3 * 16384 * 2);
  u16* wpn1T = (u16*)alloc((size_t)6 * 16384 * 2);
  u16* wpn2T = (u16*)alloc((size_t)3 * 16384 * 2);

  const size_t base_off = off;
  int* startp = (int*)alloc((size_t)(N_ + 1) * 4);
  int* cntp = (int*)alloc((size_t)N_ * 4);
  int* partp = (int*)alloc((size_t)N_ * 4);
  int* bsump = (int*)alloc(((size_t)(N_ + 255) / 256) * 4 + 256);
  int* sortedS = (int*)alloc((size_t)E_ * 4);
  int* sortedR = (int*)alloc((size_t)E_ * 4);
  bool useCSR = (off <= ws_size);
  if (!useCSR) {
    off = base_off;
    if (off > ws_size) {
      sentinel_kernel<<<(out_size + 255) / 256, 256, 0, stream>>>((float*)d_out, out_size);
      return;
    }
  }

  TArgs ta;
  int ts = 0;
  ta.s[ts++] = {F(13), wne2T};
  ta.s[ts++] = {F(19), wee2T};
  for (int i = 0; i < 3; ++i)
    for (int b = 0; b < 3; ++b)
      ta.s[ts++] = {F(23) + (size_t)(i * 3 + b) * 16384, wpe1T + (size_t)(i * 3 + b) * 16384};
  for (int i = 0; i < 3; ++i) ta.s[ts++] = {F(25) + (size_t)i * 16384, wpe2T + (size_t)i * 16384};
  for (int i = 0; i < 3; ++i)
    for (int b = 0; b < 2; ++b)
      ta.s[ts++] = {F(29) + (size_t)(i * 2 + b) * 16384, wpn1T + (size_t)(i * 2 + b) * 16384};
  for (int i = 0; i < 3; ++i) ta.s[ts++] = {F(31) + (size_t)i * 16384, wpn2T + (size_t)i * 16384};

  const int tilesN = (N_ + 63) / 64;
  const int tilesE = (E_ + 63) / 64;
  const int nb = (N_ + 255) / 256;
  dim3 blk(256);

  transpose_w<<<23, blk, 0, stream>>>(ta);

  const int* sArr = edge_index;
  const int* rArr = edge_index + E_;
  if (useCSR) {
    zero_i32<<<(N_ + 255) / 256, blk, 0, stream>>>(cntp, N_);
    deg_count<<<(E_ + 255) / 256, blk, 0, stream>>>(edge_index, cntp, E_);
    scan1<<<nb, blk, 0, stream>>>(cntp, partp, bsump, N_);
    scan2<<<1, blk, 0, stream>>>(bsump, nb);
    scan3<<<nb, blk, 0, stream>>>(partp, bsump, startp, N_);
    zero_i32<<<(N_ + 255) / 256, blk, 0, stream>>>(cntp, N_);
    fill_slot<<<(E_ + 255) / 256, blk, 0, stream>>>(edge_index, cntp, startp, sortedS, sortedR,
                                                    E_);
    sArr = sortedS;
    rArr = sortedR;
  }

  // ---- encode (fully fused 2-layer MLP + LN) ----
  node_feat_kernel<<<(N_ + 255) / 256, blk, 0, stream>>>(F(0), F(1), F(2), F(3), F(4), F(7),
                                                         F(8), nfeat, N_);
  encode_fused<9><<<tilesN, blk, 0, stream>>>(nfeat, F(11), F(12), wne2T, F(14), F(15), F(16),
                                              xh, N_);
  edge_feat_kernel<<<(E_ + 255) / 256, blk, 0, stream>>>(sArr, rArr, F(5), F(0), F(9), F(10),
                                                         efeat, E_);
  encode_fused<4><<<tilesE, blk, 0, stream>>>(efeat, F(17), F(18), wee2T, F(20), F(21), F(22),
                                              ehP, E_);

  // ---- process steps ----
  for (int i = 0; i < 3; ++i) {
    const u16* wtA = wpe1T + (size_t)(i * 3 + 0) * 16384;
    const u16* wtB = wpe1T + (size_t)(i * 3 + 1) * 16384;
    const u16* wtC = wpe1T + (size_t)(i * 3 + 2) * 16384;
    const float* pb1 = F(24) + i * 128;
    const u16* wt2 = wpe2T + (size_t)i * 16384;
    const float* pb2 = F(26) + i * 128;
    const float* pg = F(27) + i * 128;
    const float* pbe = F(28) + i * 128;
    const u16* wtnA = wpn1T + (size_t)(i * 2 + 0) * 16384;
    const u16* wtnB = wpn1T + (size_t)(i * 2 + 1) * 16384;
    const float* nb1 = F(30) + i * 128;
    const u16* wtn2 = wpn2T + (size_t)i * 16384;
    const float* nb2 = F(32) + i * 128;
    const float* ng = F(33) + i * 128;
    const float* nbe = F(34) + i * 128;

    if (i == 0)
      gemm64_2w<<<tilesN, blk, 0, stream>>>(xh, wtA, wtB, xhA, xhB, aggr, N_);
    if (useCSR) {
      edge_fused<true><<<tilesE, blk, 0, stream>>>(ehP, xhA, xhB, wtC, pb1, wt2, pb2, pg, pbe,
                                                   sArr, rArr, startp, aggr, E_);
    } else {
      edge_fused<false><<<tilesE, blk, 0, stream>>>(ehP, xhA, xhB, wtC, pb1, wt2, pb2, pg, pbe,
                                                    sArr, rArr, nullptr, aggr, E_);
    }
    const u16* wtA2 = (i < 2) ? wpe1T + (size_t)((i + 1) * 3 + 0) * 16384 : nullptr;
    const u16* wtB2 = (i < 2) ? wpe1T + (size_t)((i + 1) * 3 + 1) * 16384 : nullptr;
    node_fused_2w<<<tilesN, blk, 0, stream>>>(xh, aggr, wtnA, wtnB, nb1, wtn2, nb2, ng, nbe,
                                              wtA2, wtB2, xhA, xhB, N_);
  }

  // ---- decode ----
  decoder_kernel<<<(N_ + 3) / 4, blk, 0, stream>>>(xh, F(35), F(36), F(37), F(38),
                                                   (float*)d_out, N_);
}